// Round 12
// baseline (262.093 us; speedup 1.0000x reference)
//
#include <hip/hip_runtime.h>
#include <hip/hip_bf16.h>
#include <cstdint>

typedef __attribute__((ext_vector_type(8))) short short8;
typedef __attribute__((ext_vector_type(4))) short short4_;
typedef __attribute__((ext_vector_type(4))) float float4_;
typedef __attribute__((ext_vector_type(16))) float f32x16;

#define MFMA16(a,b,c)  __builtin_amdgcn_mfma_f32_16x16x32_bf16(a,b,c,0,0,0)
#define MFMA32(a,b,c)  __builtin_amdgcn_mfma_f32_32x32x16_bf16(a,b,c,0,0,0)
#define EXP2(x) __builtin_amdgcn_exp2f(x)

// fast bf16 RNE: bit-identical to __float2bfloat16 for all non-NaN inputs.
__device__ __forceinline__ short f2bs(float f) {
    union { float f; uint32_t u; } c;
    c.f = f;
    c.u += 0x7FFF + ((c.u >> 16) & 1);
    return (short)(c.u >> 16);
}
__device__ __forceinline__ float s2f(short s) {
    union { uint32_t u; float f; } c;
    c.u = ((uint32_t)(uint16_t)s) << 16;
    return c.f;
}

static const int EMB = 256;
static const int SEQ = 4096;   // 64*64 spatial
static const int TOK = 16384;  // BS * SEQ

static const size_t SZO = 4194304;   // shorts per O-partial (8 MB)
static const size_t LSTRIDE = 65536; // floats per l-partial (256 KB)

// Attention scale folded into wq/bq: (1/8) * log2(e) -> softmax in exp2 domain.
#define QSCALE 0.18033688011112042f

// ---------------------------------------------------------------- repack ----
__global__ __launch_bounds__(256) void repack_kernel(
    const float* wq, const float* wk, const float* wv,
    const float* wo, const float* w1, const float* w2,
    short* wqT, short* wkT, short* wvT, short* woT, short* w1T, short* w2T)
{
    int idx = blockIdx.x * 256 + threadIdx.x;
    if (idx < 3 * 4096) {
        int m = idx / 4096, r = idx % 4096;
        int n = r / 64, k = r % 64;
        const float* src = (m == 0) ? wq : (m == 1) ? wk : wv;
        short* dst = (m == 0) ? wqT : (m == 1) ? wkT : wvT;
        float v = src[k * 64 + n];
        if (m == 0) v *= QSCALE;
        dst[n * 64 + k] = f2bs(v);
    } else {
        int idx2 = idx - 3 * 4096;
        if (idx2 < 3 * 65536) {
            int m = idx2 / 65536, r = idx2 % 65536;
            int n = r / 256, k = r % 256;
            const float* src = (m == 0) ? wo : (m == 1) ? w1 : w2;
            short* dst = (m == 0) ? woT : (m == 1) ? w1T : w2T;
            dst[n * 256 + k] = f2bs(src[k * 256 + n]);
        }
    }
}

// ---------------------------------------------------------------- ln1qkv ----
// v3: 2 blocks/CU. v2 kept grid=256 (1 block/CU) — a lone block leaves the
// CU idle at its barriers/tail. Now: 512 blocks x 512 threads, 32 tokens
// each. Phase 1: 32 tokens x 16 channel-parts (v[16]/thread, single pass);
// wave-internal shfl pairs parts {2w,2w+1}, LDS combines 8 partials.
// Phase 2: 2 tiles x 4 wave-roles {q nb0-3, k nb0-3, vT nb0-1, vT nb2-3}.
// Per-wave serial work halves vs v2; two blocks interleave per CU.
// Output addressing byte-identical (each (tile,proj,nb) written once).
__global__ __launch_bounds__(512, 2) void ln1qkv_kernel(
    const float* x, const float* g, const float* bta,
    const short* wqT, const short* wkT, const short* wvT,
    const float* bq, const float* bk, const float* bv,
    short* xt, short* qo, short* ko, short* vto)
{
    __shared__ short xn_lds[32 * 264];          // 16.9 KB
    __shared__ float redS[8][32], redQ[8][32];  // 2 KB

    int tid = threadIdx.x;
    int l = tid & 31;          // token lane 0..31
    int cp = tid >> 5;         // channel part 0..15 (16 channels each)
    int t = blockIdx.x * 32 + l;
    int b = t >> 12, sp = t & 4095;
    const float* xb = x + (size_t)b * EMB * SEQ + (size_t)(cp * 16) * SEQ + sp;

    // ---- phase 1: LN ----
    float v[16];
#pragma unroll
    for (int j = 0; j < 16; j++) v[j] = xb[(size_t)j * SEQ];
    float sum = 0.f, ss = 0.f;
#pragma unroll
    for (int j = 0; j < 16; j++) { sum += v[j]; ss += v[j] * v[j]; }
    // wave w holds parts {2w, 2w+1}; lane^32 is same token, other part
    sum += __shfl_xor(sum, 32);
    ss  += __shfl_xor(ss, 32);
    int w = tid >> 6;
    if ((tid & 32) == 0) { redS[w][l] = sum; redQ[w][l] = ss; }
    __syncthreads();
    float S = 0.f, Q = 0.f;
#pragma unroll
    for (int p = 0; p < 8; p++) { S += redS[p][l]; Q += redQ[p][l]; }
    float mu = S * (1.f / 256.f);
    float var = Q * (1.f / 256.f) - mu * mu;
    float rs = rsqrtf(var + 1e-5f);

    short* xtr = xt + (size_t)t * 256 + cp * 16;
    short* xnr = xn_lds + l * 264 + cp * 16;
#pragma unroll
    for (int c = 0; c < 16; c += 8) {
        short8 ra, na;
#pragma unroll
        for (int j = 0; j < 8; j++) {
            float vv = v[c + j];
            ra[j] = f2bs(vv);
            na[j] = f2bs((vv - mu) * rs * g[cp * 16 + c + j] + bta[cp * 16 + c + j]);
        }
        *(short8*)(xtr + c) = ra;
        *(short8*)(xnr + c) = na;
    }
    __syncthreads();

    // ---- phase 2: 2 tiles x 4 wave-roles ----
    int lane = tid & 63, quad = lane >> 4, l15 = lane & 15;
    int tt = w >> 2;           // token tile 0..1
    int role = w & 3;          // 0:q 1:k 2:vT-lo 3:vT-hi
    int m0 = blockIdx.x * 32 + tt * 16;
    int row = m0 + l15;
    int bb = row >> 12;

    const short* arow = xn_lds + (tt * 16 + l15) * 264;
    short8 a0[4], a1[4];
#pragma unroll
    for (int h = 0; h < 4; h++) {
        a0[h] = *(const short8*)(arow + h * 64 + quad * 8);
        a1[h] = *(const short8*)(arow + h * 64 + 32 + quad * 8);
    }

    if (role < 2) {
        // q (role 0) or k (role 1), full nb 0..3
        const short* WT = role ? wkT : wqT;
        const float* bias = role ? bk : bq;
        float bscale = role ? 1.f : QSCALE;
        short* dst = role ? ko : qo;
        int s0 = (m0 & 4095) + quad * 4;
#pragma unroll
        for (int nb = 0; nb < 4; nb++) {
            int col = nb * 16 + l15;
            short8 b0 = *(const short8*)(WT + col * 64 + quad * 8);
            short8 b1 = *(const short8*)(WT + col * 64 + 32 + quad * 8);
            float bvv = bias[col] * bscale;
#pragma unroll
            for (int h = 0; h < 4; h++) {
                float4_ acc = {bvv, bvv, bvv, bvv};
                acc = MFMA16(a0[h], b0, acc);
                acc = MFMA16(a1[h], b1, acc);
                size_t headbase = (size_t)(bb * 4 + h) * SEQ;
#pragma unroll
                for (int r = 0; r < 4; r++)
                    dst[(headbase + s0 + r) * 64 + col] = f2bs(acc[r]);
            }
        }
    } else {
        // V^T half: role 2 -> nb{0,1}, role 3 -> nb{2,3}
        int sp0 = m0 & 4095;
#pragma unroll
        for (int nbi = 0; nbi < 2; nbi++) {
            int nb = (role - 2) * 2 + nbi;
            int colw = nb * 16 + l15;
            short8 b0 = *(const short8*)(wvT + colw * 64 + quad * 8);
            short8 b1 = *(const short8*)(wvT + colw * 64 + 32 + quad * 8);
            float4_ binit;
#pragma unroll
            for (int r = 0; r < 4; r++) binit[r] = bv[nb * 16 + quad * 4 + r];
#pragma unroll
            for (int h = 0; h < 4; h++) {
                float4_ acc = binit;
                acc = MFMA16(b0, a0[h], acc);   // A=weight rows (d), B=xn rows (token)
                acc = MFMA16(b1, a1[h], acc);
                size_t dbase = ((size_t)(bb * 4 + h) * 64 + nb * 16 + quad * 4) * SEQ;
#pragma unroll
                for (int r = 0; r < 4; r++)
                    vto[dbase + (size_t)r * SEQ + sp0 + l15] = f2bs(acc[r]);
            }
        }
    }
}

// ----------------------------------------------------------------- flash ----
// v14 (verbatim — passing, 89.3 us, VGPR 72, no spill): 32x32x16 MFMA for
// QK AND PV; all-b128 LDS in write-balanced swizzle; P redistribution via
// cvt_pk + v_permlane32_swap_b32. waves_per_eu(2,4) (min=2 -> 128-VGPR
// budget; round-5's spill was the (4,4) min forcing 64).
__global__ __attribute__((amdgpu_flat_work_group_size(256, 256),
                          amdgpu_waves_per_eu(2, 4)))
void flash_kernel(
    const short* q, const short* k, const short* vt,
    short* O0, short* Orest, float* lbase)
{
    __shared__ short K_lds[64 * 64];
    __shared__ short V_lds[64 * 64];

    int tid = threadIdx.x;
    int w = tid >> 6, lane = tid & 63;
    int l31 = lane & 31, hh = lane >> 5;
    int qt = blockIdx.x, bh = blockIdx.y, grp = blockIdx.z;
    int span = 64 / gridDim.z;              // K-tiles per block

    const short* qb = q + (size_t)bh * SEQ * 64;
    const short* kb = k + (size_t)bh * SEQ * 64 + (size_t)grp * span * 64 * 64;
    const short* vb = vt + (size_t)bh * 64 * SEQ + grp * span * 64;

    int qrow = qt * 128 + w * 32 + l31;
    // Q B-fragments: B[n=q=l31][k(d) = kb4*16 + hh*8 + j]
    short8 qf[4];
#pragma unroll
    for (int kb4 = 0; kb4 < 4; kb4++)
        qf[kb4] = *(const short8*)(qb + (size_t)qrow * 64 + kb4 * 16 + hh * 8);

    f32x16 oacc[2];   // O^T[d = td*32 + (reg&3)+8*(reg>>2)+4*hh][q = l31]
#pragma unroll
    for (int td = 0; td < 2; td++)
#pragma unroll
        for (int i = 0; i < 16; i++) oacc[td][i] = 0.f;
    float li = 0.f;

    int srow = tid >> 2;          // 0..63
    int c0 = tid & 3;             // chunk (16B units)
    // write-balanced swizzle: s(row) = (row&7) ^ ((row&1)<<2)
    int sw = (srow & 7) ^ ((srow & 1) << 2);
    int rw = (l31 & 7) ^ ((l31 & 1) << 2);

    int dcA = (c0 ^ sw) << 3;
    int dcB = ((c0 + 4) ^ sw) << 3;

    // prologue: stage tile 0 into registers
    short8 kr0 = *(const short8*)(kb + (size_t)srow * 64 + c0 * 8);
    short8 kr1 = *(const short8*)(kb + (size_t)srow * 64 + (c0 + 4) * 8);
    short8 vr0 = *(const short8*)(vb + (size_t)srow * SEQ + c0 * 8);
    short8 vr1 = *(const short8*)(vb + (size_t)srow * SEQ + (c0 + 4) * 8);

    for (int kt = 0; kt < span; kt++) {
        __syncthreads();          // prev-tile LDS reads done
        *(short8*)&K_lds[srow * 64 + dcA] = kr0;
        *(short8*)&K_lds[srow * 64 + dcB] = kr1;
        *(short8*)&V_lds[srow * 64 + dcA] = vr0;
        *(short8*)&V_lds[srow * 64 + dcB] = vr1;
        if (kt + 1 < span) {      // prefetch kt+1: stays in flight across barrier
            kr0 = *(const short8*)(kb + (size_t)((kt + 1) * 64 + srow) * 64 + c0 * 8);
            kr1 = *(const short8*)(kb + (size_t)((kt + 1) * 64 + srow) * 64 + (c0 + 4) * 8);
            vr0 = *(const short8*)(vb + (size_t)srow * SEQ + (kt + 1) * 64 + c0 * 8);
            vr1 = *(const short8*)(vb + (size_t)srow * SEQ + (kt + 1) * 64 + (c0 + 4) * 8);
        }
        asm volatile("s_waitcnt lgkmcnt(0)" ::: "memory");  // my ds_writes done
        __builtin_amdgcn_s_barrier();                       // no vmcnt(0) drain
        asm volatile("" ::: "memory");

#pragma unroll
        for (int t = 0; t < 2; t++) {
            // ---- QK^T: S[kcol = t*32 + ...][q], 4x MFMA 32x32x16 ----
            f32x16 acc;
#pragma unroll
            for (int i = 0; i < 16; i++) acc[i] = 0.f;
#pragma unroll
            for (int kb4 = 0; kb4 < 4; kb4++) {
                short8 ka = *(const short8*)&K_lds[(t * 32 + l31) * 64 +
                                                   (((kb4 * 2 + hh) ^ rw) << 3)];
                acc = MFMA32(ka, qf[kb4], acc);
            }
            // ---- exp2 (in place) + row-sum (q is lane-local) ----
#pragma unroll
            for (int i = 0; i < 16; i++) acc[i] = EXP2(acc[i]);
            li += ((acc[0] + acc[1]) + (acc[2] + acc[3]))
                + ((acc[4] + acc[5]) + (acc[6] + acc[7]))
                + ((acc[8] + acc[9]) + (acc[10] + acc[11]))
                + ((acc[12] + acc[13]) + (acc[14] + acc[15]));
            // ---- pack P -> PV B-frags via cvt_pk + permlane32_swap ----
            short8 wf[2];
#pragma unroll
            for (int kbl = 0; kbl < 2; kbl++) {
                uint32_t A0, A1, B0, B1;
                asm("v_cvt_pk_bf16_f32 %0, %1, %2" : "=v"(A0)
                    : "v"(acc[kbl * 8 + 0]), "v"(acc[kbl * 8 + 1]));
                asm("v_cvt_pk_bf16_f32 %0, %1, %2" : "=v"(A1)
                    : "v"(acc[kbl * 8 + 2]), "v"(acc[kbl * 8 + 3]));
                asm("v_cvt_pk_bf16_f32 %0, %1, %2" : "=v"(B0)
                    : "v"(acc[kbl * 8 + 4]), "v"(acc[kbl * 8 + 5]));
                asm("v_cvt_pk_bf16_f32 %0, %1, %2" : "=v"(B1)
                    : "v"(acc[kbl * 8 + 6]), "v"(acc[kbl * 8 + 7]));
                // after swap: A = [A_lo|B_lo] (= w0/w1), B = [A_hi|B_hi] (= w2/w3)
                asm("v_permlane32_swap_b32 %0, %1" : "+v"(A0), "+v"(B0));
                asm("v_permlane32_swap_b32 %0, %1" : "+v"(A1), "+v"(B1));
                union { short8 s; uint32_t u[4]; } pw;
                pw.u[0] = A0; pw.u[1] = A1; pw.u[2] = B0; pw.u[3] = B1;
                wf[kbl] = pw.s;
            }
            // ---- PV: O^T += V^T-frag x P-frag, 4x MFMA 32x32x16 ----
            __builtin_amdgcn_s_setprio(1);
#pragma unroll
            for (int kbl = 0; kbl < 2; kbl++) {
                int kc = (t * 2 + kbl) * 2 + hh;
#pragma unroll
                for (int td = 0; td < 2; td++) {
                    short8 va = *(const short8*)&V_lds[(td * 32 + l31) * 64 +
                                                       ((kc ^ rw) << 3)];
                    oacc[td] = MFMA32(va, wf[kbl], oacc[td]);
                }
            }
            __builtin_amdgcn_s_setprio(0);
        }
    }

    li += __shfl_xor(li, 32);

    short* Op = grp ? (Orest + (size_t)(grp - 1) * SZO) : O0;
    float* lp = lbase + (size_t)grp * LSTRIDE;
    if (hh == 0) lp[bh * 4096 + qrow] = li;

    size_t ob = ((size_t)bh * 4096 + qrow) * 64;
#pragma unroll
    for (int td = 0; td < 2; td++)
#pragma unroll
        for (int g = 0; g < 4; g++) {
            short4_ pk;
#pragma unroll
            for (int r = 0; r < 4; r++) pk[r] = f2bs(oacc[td][g * 4 + r]);
            *(short4_*)(Op + ob + td * 32 + g * 8 + hh * 4) = pk;
        }
}

// --------------------------------------------------------------- combine ----
// Fallback path only: out = (sum of np partials) / (sum of np l's).
__global__ __launch_bounds__(256) void combine_kernel(
    const short* O0, const short* Orest, const float* lb,
    short* Oout, int np)
{
    int g = blockIdx.x * 256 + threadIdx.x;     // short4 units, 1048576 total
    int qi = g >> 4;
    short4_ a = *(const short4_*)(O0 + (size_t)g * 4);
    float l = lb[qi];
    float4_ acc = {s2f(a[0]), s2f(a[1]), s2f(a[2]), s2f(a[3])};
    for (int j = 1; j < np; j++) {
        short4_ b = *(const short4_*)(Orest + (size_t)(j - 1) * SZO + (size_t)g * 4);
        l += lb[(size_t)j * LSTRIDE + qi];
#pragma unroll
        for (int jj = 0; jj < 4; jj++) acc[jj] += s2f(b[jj]);
    }
    float inv = 1.f / l;
    short4_ pk;
#pragma unroll
    for (int j = 0; j < 4; j++) pk[j] = f2bs(acc[j] * inv);
    *(short4_*)(Oout + (size_t)g * 4) = pk;
}

// ------------------------------------------------------------------- mlp ----
// (verbatim — passing) Fused back half with combine folded into stage A.
__global__ __launch_bounds__(256) void mlp_kernel(
    const short* O0, const short* Orest, const float* lb, int np,
    const short* woT, const short* w1T, const short* w2T,
    const float* bo, const float* b1, const float* b2,
    const float* g2, const float* be2,
    const short* xt, float* outf)
{
    __shared__ __align__(16) char smem[3 * 8448 + 128];
    short* av = (short*)smem;                   // [16][264] bf16
    short* x2 = (short*)(smem + 8448);          // [16][264] bf16
    short* ff = (short*)(smem + 16896);         // [16][264] bf16
    float* stats = (float*)(smem + 25344);      // mu[16], rs[16]
    float* T = (float*)smem;                    // alias av|x2 (16.6 KB <= 16.9)

    int tid = threadIdx.x;
    int w = tid >> 6, lane = tid & 63, quad = lane >> 4, l15 = lane & 15;
    int m0 = blockIdx.x * 16;
    int n0 = w * 64;
    int arow = m0 + l15;
    int bbA = arow >> 12, spA = arow & 4095;

    // per-(head,token) normalizers (loop-invariant, small cached loads)
    float invh[4];
    if (np) {
#pragma unroll
        for (int h = 0; h < 4; h++) {
            size_t li = (size_t)(bbA * 4 + h) * 4096 + spA;
            float s = lb[li];
            for (int j = 1; j < np; j++) s += lb[(size_t)j * LSTRIDE + li];
            invh[h] = 1.f / s;
        }
    }

    // ---- stage A: attention out-proj + xt residual -> av (LDS bf16) ----
    float4_ acc[4];
#pragma unroll
    for (int nb = 0; nb < 4; nb++) {
        float bvv = bo[n0 + nb * 16 + l15];
        acc[nb] = {bvv, bvv, bvv, bvv};
    }
    for (int kc = 0; kc < 8; kc++) {
        int h = kc >> 1;
        int off = (kc & 1) * 32 + quad * 8;
        size_t obase = ((size_t)(bbA * 4 + h) * 4096 + spA) * 64 + off;
        short8 a;
        if (np) {
            short8 a0v = *(const short8*)(O0 + obase);
            float f[8];
#pragma unroll
            for (int jj = 0; jj < 8; jj++) f[jj] = s2f(a0v[jj]);
            for (int j = 1; j < np; j++) {
                short8 apv = *(const short8*)(Orest + (size_t)(j - 1) * SZO + obase);
#pragma unroll
                for (int jj = 0; jj < 8; jj++) f[jj] += s2f(apv[jj]);
            }
            float iv = invh[h];
            union { short8 s; uint32_t u[4]; } pa;
#pragma unroll
            for (int jj = 0; jj < 4; jj++) {
                float f0 = f[2 * jj] * iv;
                float f1 = f[2 * jj + 1] * iv;
                asm("v_cvt_pk_bf16_f32 %0, %1, %2" : "=v"(pa.u[jj]) : "v"(f0), "v"(f1));
            }
            a = pa.s;
        } else {
            a = *(const short8*)(O0 + obase);
        }
#pragma unroll
        for (int nb = 0; nb < 4; nb++) {
            short8 b = *(const short8*)(woT + (size_t)(n0 + nb * 16 + l15) * 256 + kc * 32 + quad * 8);
            acc[nb] = MFMA16(a, b, acc[nb]);
        }
    }
#pragma unroll
    for (int nb = 0; nb < 4; nb++) {
        int col = n0 + nb * 16 + l15;
#pragma unroll
        for (int r = 0; r < 4; r++) {
            size_t t = (size_t)m0 + quad * 4 + r;
            av[(quad * 4 + r) * 264 + col] = f2bs(acc[nb][r] + s2f(xt[t * 256 + col]));
        }
    }
    __syncthreads();

    // ---- stage B: LN2 stats (16 threads per row, each sums 16 cols) ----
    {
        int row = tid >> 4, sub = tid & 15;
        float sum = 0.f, ss = 0.f;
        short8 v0 = *(const short8*)&av[row * 264 + sub * 16];
        short8 v1 = *(const short8*)&av[row * 264 + sub * 16 + 8];
#pragma unroll
        for (int j = 0; j < 8; j++) {
            float a = s2f(v0[j]), b = s2f(v1[j]);
            sum += a + b; ss += a * a + b * b;
        }
#pragma unroll
        for (int off = 1; off < 16; off <<= 1) {
            sum += __shfl_xor(sum, off);
            ss += __shfl_xor(ss, off);
        }
        if (sub == 0) {
            float mu = sum * (1.f / 256.f);
            float var = ss * (1.f / 256.f) - mu * mu;
            stats[row] = mu;
            stats[16 + row] = rsqrtf(var + 1e-5f);
        }
    }
    __syncthreads();

    // ---- stage C: xn2 = (av - mu) * rs * g2 + be2 (LDS bf16) ----
    {
        int row = tid >> 4, sub = tid & 15;
        float mu = stats[row], rs = stats[16 + row];
#pragma unroll
        for (int j = 0; j < 16; j += 4) {
            int c = sub * 16 + j;
            short4_ rv = *(const short4_*)&av[row * 264 + c];
            short4_ pk;
#pragma unroll
            for (int i = 0; i < 4; i++)
                pk[i] = f2bs((s2f(rv[i]) - mu) * rs * g2[c + i] + be2[c + i]);
            *(short4_*)&x2[row * 264 + c] = pk;
        }
    }
    __syncthreads();

    // ---- stage D: gemm1 + exact GELU -> ff (LDS bf16) ----
#pragma unroll
    for (int nb = 0; nb < 4; nb++) {
        float bvv = b1[n0 + nb * 16 + l15];
        acc[nb] = {bvv, bvv, bvv, bvv};
    }
    for (int kc = 0; kc < 8; kc++) {
        short8 a = *(const short8*)&x2[l15 * 264 + kc * 32 + quad * 8];
#pragma unroll
        for (int nb = 0; nb < 4; nb++) {
            short8 b = *(const short8*)(w1T + (size_t)(n0 + nb * 16 + l15) * 256 + kc * 32 + quad * 8);
            acc[nb] = MFMA16(a, b, acc[nb]);
        }
    }
#pragma unroll
    for (int nb = 0; nb < 4; nb++) {
        int col = n0 + nb * 16 + l15;
#pragma unroll
        for (int r = 0; r < 4; r++) {
            float v = acc[nb][r];
            v = 0.5f * v * (1.f + erff(v * 0.70710678118f));
            ff[(quad * 4 + r) * 264 + col] = f2bs(v);
        }
    }
    __syncthreads();

    // ---- stage E: gemm2 + av residual ----
#pragma unroll
    for (int nb = 0; nb < 4; nb++) {
        float bvv = b2[n0 + nb * 16 + l15];
        acc[nb] = {bvv, bvv, bvv, bvv};
    }
    for (int kc = 0; kc < 8; kc++) {
        short8 a = *(const short8*)&ff[l15 * 264 + kc * 32 + quad * 8];
#pragma unroll
        for (int nb = 0; nb < 4; nb++) {
            short8 b = *(const short8*)(w2T + (size_t)(n0 + nb * 16 + l15) * 256 + kc * 32 + quad * 8);
            acc[nb] = MFMA16(a, b, acc[nb]);
        }
    }
    float vout[4][4];
#pragma unroll
    for (int nb = 0; nb < 4; nb++) {
        int col = n0 + nb * 16 + l15;
#pragma unroll
        for (int r = 0; r < 4; r++)
            vout[nb][r] = acc[nb][r] + s2f(av[(quad * 4 + r) * 264 + col]);
    }
    __syncthreads();   // all reads of av/x2/ff complete before T alias writes

    // wave-private fp32 transpose -> coalesced [b][c][sp] stores
    float* tw = T + w * 1040;
#pragma unroll
    for (int nb = 0; nb < 4; nb++)
#pragma unroll
        for (int r = 0; r < 4; r++)
            tw[(quad * 4 + r) * 65 + nb * 16 + l15] = vout[nb][r];

    int bb = m0 >> 12;
    int spb = m0 & 4095;
    float* dst = outf + ((size_t)bb * 256 + n0 + lane) * SEQ + spb;
#pragma unroll
    for (int j = 0; j < 16; j += 4) {
        float4_ pk = {tw[(j + 0) * 65 + lane], tw[(j + 1) * 65 + lane],
                      tw[(j + 2) * 65 + lane], tw[(j + 3) * 65 + lane]};
        *(float4_*)(dst + j) = pk;
    }
}

// ---------------------------------------------------------------- launch ----
// Chain: repack -> ln1qkv (fused, 512 blocks x 512 thr) -> flash ->
// [combine] -> mlp. ws tiers: nz=4 fused (ws >= 57.5 MB) / nz=4 split
// (>= 49.5) / nz=2 fused (>= 41) / nz=2 split (>= 33) / nz=1.
extern "C" void kernel_launch(void* const* d_in, const int* in_sizes, int n_in,
                              void* d_out, int out_size, void* d_ws, size_t ws_size,
                              hipStream_t stream)
{
    const float* x     = (const float*)d_in[0];
    const float* ln1_g = (const float*)d_in[1];
    const float* ln1_b = (const float*)d_in[2];
    const float* wq    = (const float*)d_in[3];
    const float* bq    = (const float*)d_in[4];
    const float* wk    = (const float*)d_in[5];
    const float* bk    = (const float*)d_in[6];
    const float* wv    = (const float*)d_in[7];
    const float* bv    = (const float*)d_in[8];
    const float* wo    = (const float*)d_in[9];
    const float* bo    = (const float*)d_in[10];
    const float* ln2_g = (const float*)d_in[11];
    const float* ln2_b = (const float*)d_in[12];
    const float* w1    = (const float*)d_in[13];
    const float* b1    = (const float*)d_in[14];
    const float* w2    = (const float*)d_in[15];
    const float* b2    = (const float*)d_in[16];

    char* ws = (char*)d_ws;
    const size_t SZ_BF = (size_t)TOK * 256 * 2;  // 8 MB

    short* wqT = (short*)(ws + 0);
    short* wkT = (short*)(ws + 8192);
    short* wvT = (short*)(ws + 16384);
    short* woT = (short*)(ws + 24576);
    short* w1T = (short*)(ws + 155648);
    short* w2T = (short*)(ws + 286720);
    char* base = ws + 524288;

    short* xt  = (short*)(base);
    short* kbuf= (short*)(base + SZ_BF);
    short* vtb = (short*)(base + 2 * SZ_BF);

    const size_t need2_fb = 524288 + 3 * SZ_BF + 524288 + SZ_BF;      // 33.0 MB
    const size_t need2_fu = need2_fb + SZ_BF;                          // 41.0 MB
    const size_t need4_fb = 524288 + 3 * SZ_BF + 1048576 + 3 * SZ_BF;  // 49.5 MB
    const size_t need4_fu = need4_fb + SZ_BF;                          // 57.5 MB

    int nz, fuse;
    if (ws_size >= need4_fb)      { nz = 4; fuse = (ws_size >= need4_fu); }
    else if (ws_size >= need2_fb) { nz = 2; fuse = (ws_size >= need2_fu); }
    else                          { nz = 1; fuse = 0; }

    float* lbase;
    short* Orest;
    short* O0w;
    if (nz == 4) {
        lbase = (float*)(base + 3 * SZ_BF);                 // 4 x 256 KB
        Orest = (short*)(base + 3 * SZ_BF + 1048576);       // O1..O3
        O0w   = Orest + 3 * SZO;                            // fused only
    } else {
        lbase = (float*)(base + 3 * SZ_BF);                 // 2 x 256 KB
        Orest = (short*)(base + 3 * SZ_BF + 524288);        // O1
        O0w   = Orest + SZO;                                // fused only
    }

    short* qb  = (short*)d_out;                      // lower 8 MB
    short* upper = (short*)((char*)d_out + SZ_BF);   // upper 8 MB (O0 in split)
    short* O0  = fuse ? O0w : upper;                 // partial O (grp 0)
    short* Onrm= vtb;                                // normalized O (fallback)

    repack_kernel<<<816, 256, 0, stream>>>(wq, wk, wv, wo, w1, w2,
                                           wqT, wkT, wvT, woT, w1T, w2T);
    ln1qkv_kernel<<<TOK / 32, 512, 0, stream>>>(x, ln1_g, ln1_b,
                                                wqT, wkT, wvT, bq, bk, bv,
                                                xt, qb, kbuf, vtb);
    flash_kernel<<<dim3(32, 16, nz), 256, 0, stream>>>(qb, kbuf, vtb, O0, Orest, lbase);
    if (fuse) {
        mlp_kernel<<<TOK / 16, 256, 0, stream>>>(O0, Orest, lbase, nz,
                                                 woT, w1T, w2T, bo, b1, b2,
                                                 ln2_g, ln2_b, xt, (float*)d_out);
    } else {
        combine_kernel<<<4096, 256, 0, stream>>>(O0, Orest, lbase, Onrm, nz);
        mlp_kernel<<<TOK / 16, 256, 0, stream>>>(Onrm, Orest, lbase, 0,
                                                 woT, w1T, w2T, bo, b1, b2,
                                                 ln2_g, ln2_b, xt, (float*)d_out);
    }
}

// Round 13
// 257.534 us; speedup vs baseline: 1.0177x; 1.0177x over previous
//
#include <hip/hip_runtime.h>
#include <hip/hip_bf16.h>
#include <cstdint>

typedef __attribute__((ext_vector_type(8))) short short8;
typedef __attribute__((ext_vector_type(4))) short short4_;
typedef __attribute__((ext_vector_type(4))) float float4_;
typedef __attribute__((ext_vector_type(16))) float f32x16;

#define MFMA16(a,b,c)  __builtin_amdgcn_mfma_f32_16x16x32_bf16(a,b,c,0,0,0)
#define MFMA32(a,b,c)  __builtin_amdgcn_mfma_f32_32x32x16_bf16(a,b,c,0,0,0)
#define EXP2(x) __builtin_amdgcn_exp2f(x)

// fast bf16 RNE: bit-identical to __float2bfloat16 for all non-NaN inputs.
__device__ __forceinline__ short f2bs(float f) {
    union { float f; uint32_t u; } c;
    c.f = f;
    c.u += 0x7FFF + ((c.u >> 16) & 1);
    return (short)(c.u >> 16);
}
__device__ __forceinline__ float s2f(short s) {
    union { uint32_t u; float f; } c;
    c.u = ((uint32_t)(uint16_t)s) << 16;
    return c.f;
}

static const int EMB = 256;
static const int SEQ = 4096;   // 64*64 spatial
static const int TOK = 16384;  // BS * SEQ

static const size_t SZO = 4194304;   // shorts per O-partial (8 MB)
static const size_t LSTRIDE = 65536; // floats per l-partial (256 KB)

// Attention scale folded into wq/bq: (1/8) * log2(e) -> softmax in exp2 domain.
#define QSCALE 0.18033688011112042f

// ---------------------------------------------------------------- repack ----
__global__ __launch_bounds__(256) void repack_kernel(
    const float* wq, const float* wk, const float* wv,
    const float* wo, const float* w1, const float* w2,
    short* wqT, short* wkT, short* wvT, short* woT, short* w1T, short* w2T)
{
    int idx = blockIdx.x * 256 + threadIdx.x;
    if (idx < 3 * 4096) {
        int m = idx / 4096, r = idx % 4096;
        int n = r / 64, k = r % 64;
        const float* src = (m == 0) ? wq : (m == 1) ? wk : wv;
        short* dst = (m == 0) ? wqT : (m == 1) ? wkT : wvT;
        float v = src[k * 64 + n];
        if (m == 0) v *= QSCALE;
        dst[n * 64 + k] = f2bs(v);
    } else {
        int idx2 = idx - 3 * 4096;
        if (idx2 < 3 * 65536) {
            int m = idx2 / 65536, r = idx2 % 65536;
            int n = r / 256, k = r % 256;
            const float* src = (m == 0) ? wo : (m == 1) ? w1 : w2;
            short* dst = (m == 0) ? woT : (m == 1) ? w1T : w2T;
            dst[n * 256 + k] = f2bs(src[k * 256 + n]);
        }
    }
}

// ---------------------------------------------------------------- ln1qkv ----
// v2 (REVERT to round-11 best, 257.9 us total): 512-thread / 8-wave.
// LN phase = 64 tokens x 8 channel-parts (v[32]/thread, single pass);
// projection phase splits each 16-token tile across a WAVE PAIR — even wave:
// full q + V^T nb{0,1}; odd wave: full k + V^T nb{2,3}. Round-12's 32-token
// v3 regressed +4.2 us (doubled per-token weight reloads + barrier count).
__global__ __launch_bounds__(512, 2) void ln1qkv_kernel(
    const float* x, const float* g, const float* bta,
    const short* wqT, const short* wkT, const short* wvT,
    const float* bq, const float* bk, const float* bv,
    short* xt, short* qo, short* ko, short* vto)
{
    __shared__ short xn_lds[64 * 264];          // 33.8 KB
    __shared__ float redS[8][64], redQ[8][64];  // 4 KB

    int tid = threadIdx.x;
    int l = tid & 63;          // token lane
    int cp = tid >> 6;         // channel part 0..7 (32 channels each)
    int t = blockIdx.x * 64 + l;
    int b = t >> 12, sp = t & 4095;
    const float* xb = x + (size_t)b * EMB * SEQ + (size_t)(cp * 32) * SEQ + sp;

    // ---- phase 1: LN ----
    float v[32];
#pragma unroll
    for (int j = 0; j < 32; j++) v[j] = xb[(size_t)j * SEQ];
    float sum = 0.f, ss = 0.f;
#pragma unroll
    for (int j = 0; j < 32; j++) { sum += v[j]; ss += v[j] * v[j]; }
    redS[cp][l] = sum;
    redQ[cp][l] = ss;
    __syncthreads();
    float S = 0.f, Q = 0.f;
#pragma unroll
    for (int p = 0; p < 8; p++) { S += redS[p][l]; Q += redQ[p][l]; }
    float mu = S * (1.f / 256.f);
    float var = Q * (1.f / 256.f) - mu * mu;
    float rs = rsqrtf(var + 1e-5f);

    short* xtr = xt + (size_t)t * 256 + cp * 32;
    short* xnr = xn_lds + l * 264 + cp * 32;
#pragma unroll
    for (int c = 0; c < 32; c += 8) {
        short8 ra, na;
#pragma unroll
        for (int j = 0; j < 8; j++) {
            float vv = v[c + j];
            ra[j] = f2bs(vv);
            na[j] = f2bs((vv - mu) * rs * g[cp * 32 + c + j] + bta[cp * 32 + c + j]);
        }
        *(short8*)(xtr + c) = ra;
        *(short8*)(xnr + c) = na;
    }
    __syncthreads();

    // ---- phase 2: projections (wave pair per 16-token tile) ----
    int w = tid >> 6;          // wave 0..7
    int lane = tid & 63, quad = lane >> 4, l15 = lane & 15;
    int tt = w >> 1;           // token tile 0..3
    int odd = w & 1;
    int m0 = blockIdx.x * 64 + tt * 16;
    int row = m0 + l15;
    int bb = row >> 12;

    const short* arow = xn_lds + (tt * 16 + l15) * 264;
    short8 a0[4], a1[4];
#pragma unroll
    for (int h = 0; h < 4; h++) {
        a0[h] = *(const short8*)(arow + h * 64 + quad * 8);
        a1[h] = *(const short8*)(arow + h * 64 + 32 + quad * 8);
    }

    // q (even wave) or k (odd wave), full nb 0..3
    {
        const short* WT = odd ? wkT : wqT;
        const float* bias = odd ? bk : bq;
        float bscale = odd ? 1.f : QSCALE;
        short* dst = odd ? ko : qo;
        int s0 = (m0 & 4095) + quad * 4;
#pragma unroll
        for (int nb = 0; nb < 4; nb++) {
            int col = nb * 16 + l15;
            short8 b0 = *(const short8*)(WT + col * 64 + quad * 8);
            short8 b1 = *(const short8*)(WT + col * 64 + 32 + quad * 8);
            float bvv = bias[col] * bscale;
#pragma unroll
            for (int h = 0; h < 4; h++) {
                float4_ acc = {bvv, bvv, bvv, bvv};
                acc = MFMA16(a0[h], b0, acc);
                acc = MFMA16(a1[h], b1, acc);
                size_t headbase = (size_t)(bb * 4 + h) * SEQ;
#pragma unroll
                for (int r = 0; r < 4; r++)
                    dst[(headbase + s0 + r) * 64 + col] = f2bs(acc[r]);
            }
        }
    }

    // V^T half: even wave nb{0,1}, odd wave nb{2,3}
    {
        int sp0 = m0 & 4095;
#pragma unroll
        for (int nbi = 0; nbi < 2; nbi++) {
            int nb = odd * 2 + nbi;
            int colw = nb * 16 + l15;
            short8 b0 = *(const short8*)(wvT + colw * 64 + quad * 8);
            short8 b1 = *(const short8*)(wvT + colw * 64 + 32 + quad * 8);
            float4_ binit;
#pragma unroll
            for (int r = 0; r < 4; r++) binit[r] = bv[nb * 16 + quad * 4 + r];
#pragma unroll
            for (int h = 0; h < 4; h++) {
                float4_ acc = binit;
                acc = MFMA16(b0, a0[h], acc);   // A=weight rows (d), B=xn rows (token)
                acc = MFMA16(b1, a1[h], acc);
                size_t dbase = ((size_t)(bb * 4 + h) * 64 + nb * 16 + quad * 4) * SEQ;
#pragma unroll
                for (int r = 0; r < 4; r++)
                    vto[dbase + (size_t)r * SEQ + sp0 + l15] = f2bs(acc[r]);
            }
        }
    }
}

// ----------------------------------------------------------------- flash ----
// v14 (verbatim — passing, ~89-92 us, VGPR 72, no spill): 32x32x16 MFMA for
// QK AND PV; all-b128 LDS in write-balanced swizzle; P redistribution via
// cvt_pk + v_permlane32_swap_b32. waves_per_eu(2,4) (min=2 -> 128-VGPR
// budget; round-5's spill was the (4,4) min forcing 64).
__global__ __attribute__((amdgpu_flat_work_group_size(256, 256),
                          amdgpu_waves_per_eu(2, 4)))
void flash_kernel(
    const short* q, const short* k, const short* vt,
    short* O0, short* Orest, float* lbase)
{
    __shared__ short K_lds[64 * 64];
    __shared__ short V_lds[64 * 64];

    int tid = threadIdx.x;
    int w = tid >> 6, lane = tid & 63;
    int l31 = lane & 31, hh = lane >> 5;
    int qt = blockIdx.x, bh = blockIdx.y, grp = blockIdx.z;
    int span = 64 / gridDim.z;              // K-tiles per block

    const short* qb = q + (size_t)bh * SEQ * 64;
    const short* kb = k + (size_t)bh * SEQ * 64 + (size_t)grp * span * 64 * 64;
    const short* vb = vt + (size_t)bh * 64 * SEQ + grp * span * 64;

    int qrow = qt * 128 + w * 32 + l31;
    // Q B-fragments: B[n=q=l31][k(d) = kb4*16 + hh*8 + j]
    short8 qf[4];
#pragma unroll
    for (int kb4 = 0; kb4 < 4; kb4++)
        qf[kb4] = *(const short8*)(qb + (size_t)qrow * 64 + kb4 * 16 + hh * 8);

    f32x16 oacc[2];   // O^T[d = td*32 + (reg&3)+8*(reg>>2)+4*hh][q = l31]
#pragma unroll
    for (int td = 0; td < 2; td++)
#pragma unroll
        for (int i = 0; i < 16; i++) oacc[td][i] = 0.f;
    float li = 0.f;

    int srow = tid >> 2;          // 0..63
    int c0 = tid & 3;             // chunk (16B units)
    // write-balanced swizzle: s(row) = (row&7) ^ ((row&1)<<2)
    int sw = (srow & 7) ^ ((srow & 1) << 2);
    int rw = (l31 & 7) ^ ((l31 & 1) << 2);

    int dcA = (c0 ^ sw) << 3;
    int dcB = ((c0 + 4) ^ sw) << 3;

    // prologue: stage tile 0 into registers
    short8 kr0 = *(const short8*)(kb + (size_t)srow * 64 + c0 * 8);
    short8 kr1 = *(const short8*)(kb + (size_t)srow * 64 + (c0 + 4) * 8);
    short8 vr0 = *(const short8*)(vb + (size_t)srow * SEQ + c0 * 8);
    short8 vr1 = *(const short8*)(vb + (size_t)srow * SEQ + (c0 + 4) * 8);

    for (int kt = 0; kt < span; kt++) {
        __syncthreads();          // prev-tile LDS reads done
        *(short8*)&K_lds[srow * 64 + dcA] = kr0;
        *(short8*)&K_lds[srow * 64 + dcB] = kr1;
        *(short8*)&V_lds[srow * 64 + dcA] = vr0;
        *(short8*)&V_lds[srow * 64 + dcB] = vr1;
        if (kt + 1 < span) {      // prefetch kt+1: stays in flight across barrier
            kr0 = *(const short8*)(kb + (size_t)((kt + 1) * 64 + srow) * 64 + c0 * 8);
            kr1 = *(const short8*)(kb + (size_t)((kt + 1) * 64 + srow) * 64 + (c0 + 4) * 8);
            vr0 = *(const short8*)(vb + (size_t)srow * SEQ + (kt + 1) * 64 + c0 * 8);
            vr1 = *(const short8*)(vb + (size_t)srow * SEQ + (kt + 1) * 64 + (c0 + 4) * 8);
        }
        asm volatile("s_waitcnt lgkmcnt(0)" ::: "memory");  // my ds_writes done
        __builtin_amdgcn_s_barrier();                       // no vmcnt(0) drain
        asm volatile("" ::: "memory");

#pragma unroll
        for (int t = 0; t < 2; t++) {
            // ---- QK^T: S[kcol = t*32 + ...][q], 4x MFMA 32x32x16 ----
            f32x16 acc;
#pragma unroll
            for (int i = 0; i < 16; i++) acc[i] = 0.f;
#pragma unroll
            for (int kb4 = 0; kb4 < 4; kb4++) {
                short8 ka = *(const short8*)&K_lds[(t * 32 + l31) * 64 +
                                                   (((kb4 * 2 + hh) ^ rw) << 3)];
                acc = MFMA32(ka, qf[kb4], acc);
            }
            // ---- exp2 (in place) + row-sum (q is lane-local) ----
#pragma unroll
            for (int i = 0; i < 16; i++) acc[i] = EXP2(acc[i]);
            li += ((acc[0] + acc[1]) + (acc[2] + acc[3]))
                + ((acc[4] + acc[5]) + (acc[6] + acc[7]))
                + ((acc[8] + acc[9]) + (acc[10] + acc[11]))
                + ((acc[12] + acc[13]) + (acc[14] + acc[15]));
            // ---- pack P -> PV B-frags via cvt_pk + permlane32_swap ----
            short8 wf[2];
#pragma unroll
            for (int kbl = 0; kbl < 2; kbl++) {
                uint32_t A0, A1, B0, B1;
                asm("v_cvt_pk_bf16_f32 %0, %1, %2" : "=v"(A0)
                    : "v"(acc[kbl * 8 + 0]), "v"(acc[kbl * 8 + 1]));
                asm("v_cvt_pk_bf16_f32 %0, %1, %2" : "=v"(A1)
                    : "v"(acc[kbl * 8 + 2]), "v"(acc[kbl * 8 + 3]));
                asm("v_cvt_pk_bf16_f32 %0, %1, %2" : "=v"(B0)
                    : "v"(acc[kbl * 8 + 4]), "v"(acc[kbl * 8 + 5]));
                asm("v_cvt_pk_bf16_f32 %0, %1, %2" : "=v"(B1)
                    : "v"(acc[kbl * 8 + 6]), "v"(acc[kbl * 8 + 7]));
                // after swap: A = [A_lo|B_lo] (= w0/w1), B = [A_hi|B_hi] (= w2/w3)
                asm("v_permlane32_swap_b32 %0, %1" : "+v"(A0), "+v"(B0));
                asm("v_permlane32_swap_b32 %0, %1" : "+v"(A1), "+v"(B1));
                union { short8 s; uint32_t u[4]; } pw;
                pw.u[0] = A0; pw.u[1] = A1; pw.u[2] = B0; pw.u[3] = B1;
                wf[kbl] = pw.s;
            }
            // ---- PV: O^T += V^T-frag x P-frag, 4x MFMA 32x32x16 ----
            __builtin_amdgcn_s_setprio(1);
#pragma unroll
            for (int kbl = 0; kbl < 2; kbl++) {
                int kc = (t * 2 + kbl) * 2 + hh;
#pragma unroll
                for (int td = 0; td < 2; td++) {
                    short8 va = *(const short8*)&V_lds[(td * 32 + l31) * 64 +
                                                       ((kc ^ rw) << 3)];
                    oacc[td] = MFMA32(va, wf[kbl], oacc[td]);
                }
            }
            __builtin_amdgcn_s_setprio(0);
        }
    }

    li += __shfl_xor(li, 32);

    short* Op = grp ? (Orest + (size_t)(grp - 1) * SZO) : O0;
    float* lp = lbase + (size_t)grp * LSTRIDE;
    if (hh == 0) lp[bh * 4096 + qrow] = li;

    size_t ob = ((size_t)bh * 4096 + qrow) * 64;
#pragma unroll
    for (int td = 0; td < 2; td++)
#pragma unroll
        for (int g = 0; g < 4; g++) {
            short4_ pk;
#pragma unroll
            for (int r = 0; r < 4; r++) pk[r] = f2bs(oacc[td][g * 4 + r]);
            *(short4_*)(Op + ob + td * 32 + g * 8 + hh * 4) = pk;
        }
}

// --------------------------------------------------------------- combine ----
// Fallback path only: out = (sum of np partials) / (sum of np l's).
__global__ __launch_bounds__(256) void combine_kernel(
    const short* O0, const short* Orest, const float* lb,
    short* Oout, int np)
{
    int g = blockIdx.x * 256 + threadIdx.x;     // short4 units, 1048576 total
    int qi = g >> 4;
    short4_ a = *(const short4_*)(O0 + (size_t)g * 4);
    float l = lb[qi];
    float4_ acc = {s2f(a[0]), s2f(a[1]), s2f(a[2]), s2f(a[3])};
    for (int j = 1; j < np; j++) {
        short4_ b = *(const short4_*)(Orest + (size_t)(j - 1) * SZO + (size_t)g * 4);
        l += lb[(size_t)j * LSTRIDE + qi];
#pragma unroll
        for (int jj = 0; jj < 4; jj++) acc[jj] += s2f(b[jj]);
    }
    float inv = 1.f / l;
    short4_ pk;
#pragma unroll
    for (int j = 0; j < 4; j++) pk[j] = f2bs(acc[j] * inv);
    *(short4_*)(Oout + (size_t)g * 4) = pk;
}

// ------------------------------------------------------------------- mlp ----
// (verbatim — passing) Fused back half with combine folded into stage A.
__global__ __launch_bounds__(256) void mlp_kernel(
    const short* O0, const short* Orest, const float* lb, int np,
    const short* woT, const short* w1T, const short* w2T,
    const float* bo, const float* b1, const float* b2,
    const float* g2, const float* be2,
    const short* xt, float* outf)
{
    __shared__ __align__(16) char smem[3 * 8448 + 128];
    short* av = (short*)smem;                   // [16][264] bf16
    short* x2 = (short*)(smem + 8448);          // [16][264] bf16
    short* ff = (short*)(smem + 16896);         // [16][264] bf16
    float* stats = (float*)(smem + 25344);      // mu[16], rs[16]
    float* T = (float*)smem;                    // alias av|x2 (16.6 KB <= 16.9)

    int tid = threadIdx.x;
    int w = tid >> 6, lane = tid & 63, quad = lane >> 4, l15 = lane & 15;
    int m0 = blockIdx.x * 16;
    int n0 = w * 64;
    int arow = m0 + l15;
    int bbA = arow >> 12, spA = arow & 4095;

    // per-(head,token) normalizers (loop-invariant, small cached loads)
    float invh[4];
    if (np) {
#pragma unroll
        for (int h = 0; h < 4; h++) {
            size_t li = (size_t)(bbA * 4 + h) * 4096 + spA;
            float s = lb[li];
            for (int j = 1; j < np; j++) s += lb[(size_t)j * LSTRIDE + li];
            invh[h] = 1.f / s;
        }
    }

    // ---- stage A: attention out-proj + xt residual -> av (LDS bf16) ----
    float4_ acc[4];
#pragma unroll
    for (int nb = 0; nb < 4; nb++) {
        float bvv = bo[n0 + nb * 16 + l15];
        acc[nb] = {bvv, bvv, bvv, bvv};
    }
    for (int kc = 0; kc < 8; kc++) {
        int h = kc >> 1;
        int off = (kc & 1) * 32 + quad * 8;
        size_t obase = ((size_t)(bbA * 4 + h) * 4096 + spA) * 64 + off;
        short8 a;
        if (np) {
            short8 a0v = *(const short8*)(O0 + obase);
            float f[8];
#pragma unroll
            for (int jj = 0; jj < 8; jj++) f[jj] = s2f(a0v[jj]);
            for (int j = 1; j < np; j++) {
                short8 apv = *(const short8*)(Orest + (size_t)(j - 1) * SZO + obase);
#pragma unroll
                for (int jj = 0; jj < 8; jj++) f[jj] += s2f(apv[jj]);
            }
            float iv = invh[h];
            union { short8 s; uint32_t u[4]; } pa;
#pragma unroll
            for (int jj = 0; jj < 4; jj++) {
                float f0 = f[2 * jj] * iv;
                float f1 = f[2 * jj + 1] * iv;
                asm("v_cvt_pk_bf16_f32 %0, %1, %2" : "=v"(pa.u[jj]) : "v"(f0), "v"(f1));
            }
            a = pa.s;
        } else {
            a = *(const short8*)(O0 + obase);
        }
#pragma unroll
        for (int nb = 0; nb < 4; nb++) {
            short8 b = *(const short8*)(woT + (size_t)(n0 + nb * 16 + l15) * 256 + kc * 32 + quad * 8);
            acc[nb] = MFMA16(a, b, acc[nb]);
        }
    }
#pragma unroll
    for (int nb = 0; nb < 4; nb++) {
        int col = n0 + nb * 16 + l15;
#pragma unroll
        for (int r = 0; r < 4; r++) {
            size_t t = (size_t)m0 + quad * 4 + r;
            av[(quad * 4 + r) * 264 + col] = f2bs(acc[nb][r] + s2f(xt[t * 256 + col]));
        }
    }
    __syncthreads();

    // ---- stage B: LN2 stats (16 threads per row, each sums 16 cols) ----
    {
        int row = tid >> 4, sub = tid & 15;
        float sum = 0.f, ss = 0.f;
        short8 v0 = *(const short8*)&av[row * 264 + sub * 16];
        short8 v1 = *(const short8*)&av[row * 264 + sub * 16 + 8];
#pragma unroll
        for (int j = 0; j < 8; j++) {
            float a = s2f(v0[j]), b = s2f(v1[j]);
            sum += a + b; ss += a * a + b * b;
        }
#pragma unroll
        for (int off = 1; off < 16; off <<= 1) {
            sum += __shfl_xor(sum, off);
            ss += __shfl_xor(ss, off);
        }
        if (sub == 0) {
            float mu = sum * (1.f / 256.f);
            float var = ss * (1.f / 256.f) - mu * mu;
            stats[row] = mu;
            stats[16 + row] = rsqrtf(var + 1e-5f);
        }
    }
    __syncthreads();

    // ---- stage C: xn2 = (av - mu) * rs * g2 + be2 (LDS bf16) ----
    {
        int row = tid >> 4, sub = tid & 15;
        float mu = stats[row], rs = stats[16 + row];
#pragma unroll
        for (int j = 0; j < 16; j += 4) {
            int c = sub * 16 + j;
            short4_ rv = *(const short4_*)&av[row * 264 + c];
            short4_ pk;
#pragma unroll
            for (int i = 0; i < 4; i++)
                pk[i] = f2bs((s2f(rv[i]) - mu) * rs * g2[c + i] + be2[c + i]);
            *(short4_*)&x2[row * 264 + c] = pk;
        }
    }
    __syncthreads();

    // ---- stage D: gemm1 + exact GELU -> ff (LDS bf16) ----
#pragma unroll
    for (int nb = 0; nb < 4; nb++) {
        float bvv = b1[n0 + nb * 16 + l15];
        acc[nb] = {bvv, bvv, bvv, bvv};
    }
    for (int kc = 0; kc < 8; kc++) {
        short8 a = *(const short8*)&x2[l15 * 264 + kc * 32 + quad * 8];
#pragma unroll
        for (int nb = 0; nb < 4; nb++) {
            short8 b = *(const short8*)(w1T + (size_t)(n0 + nb * 16 + l15) * 256 + kc * 32 + quad * 8);
            acc[nb] = MFMA16(a, b, acc[nb]);
        }
    }
#pragma unroll
    for (int nb = 0; nb < 4; nb++) {
        int col = n0 + nb * 16 + l15;
#pragma unroll
        for (int r = 0; r < 4; r++) {
            float v = acc[nb][r];
            v = 0.5f * v * (1.f + erff(v * 0.70710678118f));
            ff[(quad * 4 + r) * 264 + col] = f2bs(v);
        }
    }
    __syncthreads();

    // ---- stage E: gemm2 + av residual ----
#pragma unroll
    for (int nb = 0; nb < 4; nb++) {
        float bvv = b2[n0 + nb * 16 + l15];
        acc[nb] = {bvv, bvv, bvv, bvv};
    }
    for (int kc = 0; kc < 8; kc++) {
        short8 a = *(const short8*)&ff[l15 * 264 + kc * 32 + quad * 8];
#pragma unroll
        for (int nb = 0; nb < 4; nb++) {
            short8 b = *(const short8*)(w2T + (size_t)(n0 + nb * 16 + l15) * 256 + kc * 32 + quad * 8);
            acc[nb] = MFMA16(a, b, acc[nb]);
        }
    }
    float vout[4][4];
#pragma unroll
    for (int nb = 0; nb < 4; nb++) {
        int col = n0 + nb * 16 + l15;
#pragma unroll
        for (int r = 0; r < 4; r++)
            vout[nb][r] = acc[nb][r] + s2f(av[(quad * 4 + r) * 264 + col]);
    }
    __syncthreads();   // all reads of av/x2/ff complete before T alias writes

    // wave-private fp32 transpose -> coalesced [b][c][sp] stores
    float* tw = T + w * 1040;
#pragma unroll
    for (int nb = 0; nb < 4; nb++)
#pragma unroll
        for (int r = 0; r < 4; r++)
            tw[(quad * 4 + r) * 65 + nb * 16 + l15] = vout[nb][r];

    int bb = m0 >> 12;
    int spb = m0 & 4095;
    float* dst = outf + ((size_t)bb * 256 + n0 + lane) * SEQ + spb;
#pragma unroll
    for (int j = 0; j < 16; j += 4) {
        float4_ pk = {tw[(j + 0) * 65 + lane], tw[(j + 1) * 65 + lane],
                      tw[(j + 2) * 65 + lane], tw[(j + 3) * 65 + lane]};
        *(float4_*)(dst + j) = pk;
    }
}

// ---------------------------------------------------------------- launch ----
// Chain: repack -> ln1qkv (fused, 256 blocks x 512 thr) -> flash ->
// [combine] -> mlp. ws tiers: nz=4 fused (ws >= 57.5 MB) / nz=4 split
// (>= 49.5) / nz=2 fused (>= 41) / nz=2 split (>= 33) / nz=1.
extern "C" void kernel_launch(void* const* d_in, const int* in_sizes, int n_in,
                              void* d_out, int out_size, void* d_ws, size_t ws_size,
                              hipStream_t stream)
{
    const float* x     = (const float*)d_in[0];
    const float* ln1_g = (const float*)d_in[1];
    const float* ln1_b = (const float*)d_in[2];
    const float* wq    = (const float*)d_in[3];
    const float* bq    = (const float*)d_in[4];
    const float* wk    = (const float*)d_in[5];
    const float* bk    = (const float*)d_in[6];
    const float* wv    = (const float*)d_in[7];
    const float* bv    = (const float*)d_in[8];
    const float* wo    = (const float*)d_in[9];
    const float* bo    = (const float*)d_in[10];
    const float* ln2_g = (const float*)d_in[11];
    const float* ln2_b = (const float*)d_in[12];
    const float* w1    = (const float*)d_in[13];
    const float* b1    = (const float*)d_in[14];
    const float* w2    = (const float*)d_in[15];
    const float* b2    = (const float*)d_in[16];

    char* ws = (char*)d_ws;
    const size_t SZ_BF = (size_t)TOK * 256 * 2;  // 8 MB

    short* wqT = (short*)(ws + 0);
    short* wkT = (short*)(ws + 8192);
    short* wvT = (short*)(ws + 16384);
    short* woT = (short*)(ws + 24576);
    short* w1T = (short*)(ws + 155648);
    short* w2T = (short*)(ws + 286720);
    char* base = ws + 524288;

    short* xt  = (short*)(base);
    short* kbuf= (short*)(base + SZ_BF);
    short* vtb = (short*)(base + 2 * SZ_BF);

    const size_t need2_fb = 524288 + 3 * SZ_BF + 524288 + SZ_BF;      // 33.0 MB
    const size_t need2_fu = need2_fb + SZ_BF;                          // 41.0 MB
    const size_t need4_fb = 524288 + 3 * SZ_BF + 1048576 + 3 * SZ_BF;  // 49.5 MB
    const size_t need4_fu = need4_fb + SZ_BF;                          // 57.5 MB

    int nz, fuse;
    if (ws_size >= need4_fb)      { nz = 4; fuse = (ws_size >= need4_fu); }
    else if (ws_size >= need2_fb) { nz = 2; fuse = (ws_size >= need2_fu); }
    else                          { nz = 1; fuse = 0; }

    float* lbase;
    short* Orest;
    short* O0w;
    if (nz == 4) {
        lbase = (float*)(base + 3 * SZ_BF);                 // 4 x 256 KB
        Orest = (short*)(base + 3 * SZ_BF + 1048576);       // O1..O3
        O0w   = Orest + 3 * SZO;                            // fused only
    } else {
        lbase = (float*)(base + 3 * SZ_BF);                 // 2 x 256 KB
        Orest = (short*)(base + 3 * SZ_BF + 524288);        // O1
        O0w   = Orest + SZO;                                // fused only
    }

    short* qb  = (short*)d_out;                      // lower 8 MB
    short* upper = (short*)((char*)d_out + SZ_BF);   // upper 8 MB (O0 in split)
    short* O0  = fuse ? O0w : upper;                 // partial O (grp 0)
    short* Onrm= vtb;                                // normalized O (fallback)

    repack_kernel<<<816, 256, 0, stream>>>(wq, wk, wv, wo, w1, w2,
                                           wqT, wkT, wvT, woT, w1T, w2T);
    ln1qkv_kernel<<<TOK / 64, 512, 0, stream>>>(x, ln1_g, ln1_b,
                                                wqT, wkT, wvT, bq, bk, bv,
                                                xt, qb, kbuf, vtb);
    flash_kernel<<<dim3(32, 16, nz), 256, 0, stream>>>(qb, kbuf, vtb, O0, Orest, lbase);
    if (fuse) {
        mlp_kernel<<<TOK / 16, 256, 0, stream>>>(O0, Orest, lbase, nz,
                                                 woT, w1T, w2T, bo, b1, b2,
                                                 ln2_g, ln2_b, xt, (float*)d_out);
    } else {
        combine_kernel<<<4096, 256, 0, stream>>>(O0, Orest, lbase, Onrm, nz);
        mlp_kernel<<<TOK / 16, 256, 0, stream>>>(Onrm, Orest, lbase, 0,
                                                 woT, w1T, w2T, bo, b1, b2,
                                                 ln2_g, ln2_b, xt, (float*)d_out);
    }
}

// Round 14
// 252.227 us; speedup vs baseline: 1.0391x; 1.0210x over previous
//
#include <hip/hip_runtime.h>
#include <hip/hip_bf16.h>
#include <cstdint>

typedef __attribute__((ext_vector_type(8))) short short8;
typedef __attribute__((ext_vector_type(4))) short short4_;
typedef __attribute__((ext_vector_type(4))) float float4_;
typedef __attribute__((ext_vector_type(16))) float f32x16;

#define MFMA16(a,b,c)  __builtin_amdgcn_mfma_f32_16x16x32_bf16(a,b,c,0,0,0)
#define MFMA32(a,b,c)  __builtin_amdgcn_mfma_f32_32x32x16_bf16(a,b,c,0,0,0)
#define EXP2(x) __builtin_amdgcn_exp2f(x)

// fast bf16 RNE: bit-identical to __float2bfloat16 for all non-NaN inputs.
__device__ __forceinline__ short f2bs(float f) {
    union { float f; uint32_t u; } c;
    c.f = f;
    c.u += 0x7FFF + ((c.u >> 16) & 1);
    return (short)(c.u >> 16);
}
__device__ __forceinline__ float s2f(short s) {
    union { uint32_t u; float f; } c;
    c.u = ((uint32_t)(uint16_t)s) << 16;
    return c.f;
}

static const int EMB = 256;
static const int SEQ = 4096;   // 64*64 spatial
static const int TOK = 16384;  // BS * SEQ

static const size_t SZO = 4194304;   // shorts per O-partial (8 MB)
static const size_t LSTRIDE = 65536; // floats per l-partial (256 KB)

// Attention scale folded into wq/bq: (1/8) * log2(e) -> softmax in exp2 domain.
#define QSCALE 0.18033688011112042f

// ---------------------------------------------------------------- repack ----
__global__ __launch_bounds__(256) void repack_kernel(
    const float* wq, const float* wk, const float* wv,
    const float* wo, const float* w1, const float* w2,
    short* wqT, short* wkT, short* wvT, short* woT, short* w1T, short* w2T)
{
    int idx = blockIdx.x * 256 + threadIdx.x;
    if (idx < 3 * 4096) {
        int m = idx / 4096, r = idx % 4096;
        int n = r / 64, k = r % 64;
        const float* src = (m == 0) ? wq : (m == 1) ? wk : wv;
        short* dst = (m == 0) ? wqT : (m == 1) ? wkT : wvT;
        float v = src[k * 64 + n];
        if (m == 0) v *= QSCALE;
        dst[n * 64 + k] = f2bs(v);
    } else {
        int idx2 = idx - 3 * 4096;
        if (idx2 < 3 * 65536) {
            int m = idx2 / 65536, r = idx2 % 65536;
            int n = r / 256, k = r % 256;
            const float* src = (m == 0) ? wo : (m == 1) ? w1 : w2;
            short* dst = (m == 0) ? woT : (m == 1) ? w1T : w2T;
            dst[n * 256 + k] = f2bs(src[k * 256 + n]);
        }
    }
}

// ---------------------------------------------------------------- ln1qkv ----
// v2 (verbatim — round-11/13 best): 512-thread / 8-wave.
// LN phase = 64 tokens x 8 channel-parts (v[32]/thread, single pass);
// projection phase splits each 16-token tile across a WAVE PAIR — even wave:
// full q + V^T nb{0,1}; odd wave: full k + V^T nb{2,3}.
__global__ __launch_bounds__(512, 2) void ln1qkv_kernel(
    const float* x, const float* g, const float* bta,
    const short* wqT, const short* wkT, const short* wvT,
    const float* bq, const float* bk, const float* bv,
    short* xt, short* qo, short* ko, short* vto)
{
    __shared__ short xn_lds[64 * 264];          // 33.8 KB
    __shared__ float redS[8][64], redQ[8][64];  // 4 KB

    int tid = threadIdx.x;
    int l = tid & 63;          // token lane
    int cp = tid >> 6;         // channel part 0..7 (32 channels each)
    int t = blockIdx.x * 64 + l;
    int b = t >> 12, sp = t & 4095;
    const float* xb = x + (size_t)b * EMB * SEQ + (size_t)(cp * 32) * SEQ + sp;

    // ---- phase 1: LN ----
    float v[32];
#pragma unroll
    for (int j = 0; j < 32; j++) v[j] = xb[(size_t)j * SEQ];
    float sum = 0.f, ss = 0.f;
#pragma unroll
    for (int j = 0; j < 32; j++) { sum += v[j]; ss += v[j] * v[j]; }
    redS[cp][l] = sum;
    redQ[cp][l] = ss;
    __syncthreads();
    float S = 0.f, Q = 0.f;
#pragma unroll
    for (int p = 0; p < 8; p++) { S += redS[p][l]; Q += redQ[p][l]; }
    float mu = S * (1.f / 256.f);
    float var = Q * (1.f / 256.f) - mu * mu;
    float rs = rsqrtf(var + 1e-5f);

    short* xtr = xt + (size_t)t * 256 + cp * 32;
    short* xnr = xn_lds + l * 264 + cp * 32;
#pragma unroll
    for (int c = 0; c < 32; c += 8) {
        short8 ra, na;
#pragma unroll
        for (int j = 0; j < 8; j++) {
            float vv = v[c + j];
            ra[j] = f2bs(vv);
            na[j] = f2bs((vv - mu) * rs * g[cp * 32 + c + j] + bta[cp * 32 + c + j]);
        }
        *(short8*)(xtr + c) = ra;
        *(short8*)(xnr + c) = na;
    }
    __syncthreads();

    // ---- phase 2: projections (wave pair per 16-token tile) ----
    int w = tid >> 6;          // wave 0..7
    int lane = tid & 63, quad = lane >> 4, l15 = lane & 15;
    int tt = w >> 1;           // token tile 0..3
    int odd = w & 1;
    int m0 = blockIdx.x * 64 + tt * 16;
    int row = m0 + l15;
    int bb = row >> 12;

    const short* arow = xn_lds + (tt * 16 + l15) * 264;
    short8 a0[4], a1[4];
#pragma unroll
    for (int h = 0; h < 4; h++) {
        a0[h] = *(const short8*)(arow + h * 64 + quad * 8);
        a1[h] = *(const short8*)(arow + h * 64 + 32 + quad * 8);
    }

    // q (even wave) or k (odd wave), full nb 0..3
    {
        const short* WT = odd ? wkT : wqT;
        const float* bias = odd ? bk : bq;
        float bscale = odd ? 1.f : QSCALE;
        short* dst = odd ? ko : qo;
        int s0 = (m0 & 4095) + quad * 4;
#pragma unroll
        for (int nb = 0; nb < 4; nb++) {
            int col = nb * 16 + l15;
            short8 b0 = *(const short8*)(WT + col * 64 + quad * 8);
            short8 b1 = *(const short8*)(WT + col * 64 + 32 + quad * 8);
            float bvv = bias[col] * bscale;
#pragma unroll
            for (int h = 0; h < 4; h++) {
                float4_ acc = {bvv, bvv, bvv, bvv};
                acc = MFMA16(a0[h], b0, acc);
                acc = MFMA16(a1[h], b1, acc);
                size_t headbase = (size_t)(bb * 4 + h) * SEQ;
#pragma unroll
                for (int r = 0; r < 4; r++)
                    dst[(headbase + s0 + r) * 64 + col] = f2bs(acc[r]);
            }
        }
    }

    // V^T half: even wave nb{0,1}, odd wave nb{2,3}
    {
        int sp0 = m0 & 4095;
#pragma unroll
        for (int nbi = 0; nbi < 2; nbi++) {
            int nb = odd * 2 + nbi;
            int colw = nb * 16 + l15;
            short8 b0 = *(const short8*)(wvT + colw * 64 + quad * 8);
            short8 b1 = *(const short8*)(wvT + colw * 64 + 32 + quad * 8);
            float4_ binit;
#pragma unroll
            for (int r = 0; r < 4; r++) binit[r] = bv[nb * 16 + quad * 4 + r];
#pragma unroll
            for (int h = 0; h < 4; h++) {
                float4_ acc = binit;
                acc = MFMA16(b0, a0[h], acc);   // A=weight rows (d), B=xn rows (token)
                acc = MFMA16(b1, a1[h], acc);
                size_t dbase = ((size_t)(bb * 4 + h) * 64 + nb * 16 + quad * 4) * SEQ;
#pragma unroll
                for (int r = 0; r < 4; r++)
                    vto[dbase + (size_t)r * SEQ + sp0 + l15] = f2bs(acc[r]);
            }
        }
    }
}

// ----------------------------------------------------------------- flash ----
// v14 (verbatim — passing, ~90 us, VGPR 72, no spill): 32x32x16 MFMA for
// QK AND PV; all-b128 LDS in write-balanced swizzle; P redistribution via
// cvt_pk + v_permlane32_swap_b32. waves_per_eu(2,4).
__global__ __attribute__((amdgpu_flat_work_group_size(256, 256),
                          amdgpu_waves_per_eu(2, 4)))
void flash_kernel(
    const short* q, const short* k, const short* vt,
    short* O0, short* Orest, float* lbase)
{
    __shared__ short K_lds[64 * 64];
    __shared__ short V_lds[64 * 64];

    int tid = threadIdx.x;
    int w = tid >> 6, lane = tid & 63;
    int l31 = lane & 31, hh = lane >> 5;
    int qt = blockIdx.x, bh = blockIdx.y, grp = blockIdx.z;
    int span = 64 / gridDim.z;              // K-tiles per block

    const short* qb = q + (size_t)bh * SEQ * 64;
    const short* kb = k + (size_t)bh * SEQ * 64 + (size_t)grp * span * 64 * 64;
    const short* vb = vt + (size_t)bh * 64 * SEQ + grp * span * 64;

    int qrow = qt * 128 + w * 32 + l31;
    // Q B-fragments: B[n=q=l31][k(d) = kb4*16 + hh*8 + j]
    short8 qf[4];
#pragma unroll
    for (int kb4 = 0; kb4 < 4; kb4++)
        qf[kb4] = *(const short8*)(qb + (size_t)qrow * 64 + kb4 * 16 + hh * 8);

    f32x16 oacc[2];   // O^T[d = td*32 + (reg&3)+8*(reg>>2)+4*hh][q = l31]
#pragma unroll
    for (int td = 0; td < 2; td++)
#pragma unroll
        for (int i = 0; i < 16; i++) oacc[td][i] = 0.f;
    float li = 0.f;

    int srow = tid >> 2;          // 0..63
    int c0 = tid & 3;             // chunk (16B units)
    // write-balanced swizzle: s(row) = (row&7) ^ ((row&1)<<2)
    int sw = (srow & 7) ^ ((srow & 1) << 2);
    int rw = (l31 & 7) ^ ((l31 & 1) << 2);

    int dcA = (c0 ^ sw) << 3;
    int dcB = ((c0 + 4) ^ sw) << 3;

    // prologue: stage tile 0 into registers
    short8 kr0 = *(const short8*)(kb + (size_t)srow * 64 + c0 * 8);
    short8 kr1 = *(const short8*)(kb + (size_t)srow * 64 + (c0 + 4) * 8);
    short8 vr0 = *(const short8*)(vb + (size_t)srow * SEQ + c0 * 8);
    short8 vr1 = *(const short8*)(vb + (size_t)srow * SEQ + (c0 + 4) * 8);

    for (int kt = 0; kt < span; kt++) {
        __syncthreads();          // prev-tile LDS reads done
        *(short8*)&K_lds[srow * 64 + dcA] = kr0;
        *(short8*)&K_lds[srow * 64 + dcB] = kr1;
        *(short8*)&V_lds[srow * 64 + dcA] = vr0;
        *(short8*)&V_lds[srow * 64 + dcB] = vr1;
        if (kt + 1 < span) {      // prefetch kt+1: stays in flight across barrier
            kr0 = *(const short8*)(kb + (size_t)((kt + 1) * 64 + srow) * 64 + c0 * 8);
            kr1 = *(const short8*)(kb + (size_t)((kt + 1) * 64 + srow) * 64 + (c0 + 4) * 8);
            vr0 = *(const short8*)(vb + (size_t)srow * SEQ + (kt + 1) * 64 + c0 * 8);
            vr1 = *(const short8*)(vb + (size_t)srow * SEQ + (kt + 1) * 64 + (c0 + 4) * 8);
        }
        asm volatile("s_waitcnt lgkmcnt(0)" ::: "memory");  // my ds_writes done
        __builtin_amdgcn_s_barrier();                       // no vmcnt(0) drain
        asm volatile("" ::: "memory");

#pragma unroll
        for (int t = 0; t < 2; t++) {
            // ---- QK^T: S[kcol = t*32 + ...][q], 4x MFMA 32x32x16 ----
            f32x16 acc;
#pragma unroll
            for (int i = 0; i < 16; i++) acc[i] = 0.f;
#pragma unroll
            for (int kb4 = 0; kb4 < 4; kb4++) {
                short8 ka = *(const short8*)&K_lds[(t * 32 + l31) * 64 +
                                                   (((kb4 * 2 + hh) ^ rw) << 3)];
                acc = MFMA32(ka, qf[kb4], acc);
            }
            // ---- exp2 (in place) + row-sum (q is lane-local) ----
#pragma unroll
            for (int i = 0; i < 16; i++) acc[i] = EXP2(acc[i]);
            li += ((acc[0] + acc[1]) + (acc[2] + acc[3]))
                + ((acc[4] + acc[5]) + (acc[6] + acc[7]))
                + ((acc[8] + acc[9]) + (acc[10] + acc[11]))
                + ((acc[12] + acc[13]) + (acc[14] + acc[15]));
            // ---- pack P -> PV B-frags via cvt_pk + permlane32_swap ----
            short8 wf[2];
#pragma unroll
            for (int kbl = 0; kbl < 2; kbl++) {
                uint32_t A0, A1, B0, B1;
                asm("v_cvt_pk_bf16_f32 %0, %1, %2" : "=v"(A0)
                    : "v"(acc[kbl * 8 + 0]), "v"(acc[kbl * 8 + 1]));
                asm("v_cvt_pk_bf16_f32 %0, %1, %2" : "=v"(A1)
                    : "v"(acc[kbl * 8 + 2]), "v"(acc[kbl * 8 + 3]));
                asm("v_cvt_pk_bf16_f32 %0, %1, %2" : "=v"(B0)
                    : "v"(acc[kbl * 8 + 4]), "v"(acc[kbl * 8 + 5]));
                asm("v_cvt_pk_bf16_f32 %0, %1, %2" : "=v"(B1)
                    : "v"(acc[kbl * 8 + 6]), "v"(acc[kbl * 8 + 7]));
                // after swap: A = [A_lo|B_lo] (= w0/w1), B = [A_hi|B_hi] (= w2/w3)
                asm("v_permlane32_swap_b32 %0, %1" : "+v"(A0), "+v"(B0));
                asm("v_permlane32_swap_b32 %0, %1" : "+v"(A1), "+v"(B1));
                union { short8 s; uint32_t u[4]; } pw;
                pw.u[0] = A0; pw.u[1] = A1; pw.u[2] = B0; pw.u[3] = B1;
                wf[kbl] = pw.s;
            }
            // ---- PV: O^T += V^T-frag x P-frag, 4x MFMA 32x32x16 ----
            __builtin_amdgcn_s_setprio(1);
#pragma unroll
            for (int kbl = 0; kbl < 2; kbl++) {
                int kc = (t * 2 + kbl) * 2 + hh;
#pragma unroll
                for (int td = 0; td < 2; td++) {
                    short8 va = *(const short8*)&V_lds[(td * 32 + l31) * 64 +
                                                       ((kc ^ rw) << 3)];
                    oacc[td] = MFMA32(va, wf[kbl], oacc[td]);
                }
            }
            __builtin_amdgcn_s_setprio(0);
        }
    }

    li += __shfl_xor(li, 32);

    short* Op = grp ? (Orest + (size_t)(grp - 1) * SZO) : O0;
    float* lp = lbase + (size_t)grp * LSTRIDE;
    if (hh == 0) lp[bh * 4096 + qrow] = li;

    size_t ob = ((size_t)bh * 4096 + qrow) * 64;
#pragma unroll
    for (int td = 0; td < 2; td++)
#pragma unroll
        for (int g = 0; g < 4; g++) {
            short4_ pk;
#pragma unroll
            for (int r = 0; r < 4; r++) pk[r] = f2bs(oacc[td][g * 4 + r]);
            *(short4_*)(Op + ob + td * 32 + g * 8 + hh * 4) = pk;
        }
}

// --------------------------------------------------------------- combine ----
// Fallback path only: out = (sum of np partials) / (sum of np l's).
__global__ __launch_bounds__(256) void combine_kernel(
    const short* O0, const short* Orest, const float* lb,
    short* Oout, int np)
{
    int g = blockIdx.x * 256 + threadIdx.x;     // short4 units, 1048576 total
    int qi = g >> 4;
    short4_ a = *(const short4_*)(O0 + (size_t)g * 4);
    float l = lb[qi];
    float4_ acc = {s2f(a[0]), s2f(a[1]), s2f(a[2]), s2f(a[3])};
    for (int j = 1; j < np; j++) {
        short4_ b = *(const short4_*)(Orest + (size_t)(j - 1) * SZO + (size_t)g * 4);
        l += lb[(size_t)j * LSTRIDE + qi];
#pragma unroll
        for (int jj = 0; jj < 4; jj++) acc[jj] += s2f(b[jj]);
    }
    float inv = 1.f / l;
    short4_ pk;
#pragma unroll
    for (int j = 0; j < 4; j++) pk[j] = f2bs(acc[j] * inv);
    *(short4_*)(Oout + (size_t)g * 4) = pk;
}

// ------------------------------------------------------------------- mlp ----
// (verbatim — passing) Fused back half with combine folded into stage A.
__global__ __launch_bounds__(256) void mlp_kernel(
    const short* O0, const short* Orest, const float* lb, int np,
    const short* woT, const short* w1T, const short* w2T,
    const float* bo, const float* b1, const float* b2,
    const float* g2, const float* be2,
    const short* xt, float* outf)
{
    __shared__ __align__(16) char smem[3 * 8448 + 128];
    short* av = (short*)smem;                   // [16][264] bf16
    short* x2 = (short*)(smem + 8448);          // [16][264] bf16
    short* ff = (short*)(smem + 16896);         // [16][264] bf16
    float* stats = (float*)(smem + 25344);      // mu[16], rs[16]
    float* T = (float*)smem;                    // alias av|x2 (16.6 KB <= 16.9)

    int tid = threadIdx.x;
    int w = tid >> 6, lane = tid & 63, quad = lane >> 4, l15 = lane & 15;
    int m0 = blockIdx.x * 16;
    int n0 = w * 64;
    int arow = m0 + l15;
    int bbA = arow >> 12, spA = arow & 4095;

    // per-(head,token) normalizers (loop-invariant, small cached loads)
    float invh[4];
    if (np) {
#pragma unroll
        for (int h = 0; h < 4; h++) {
            size_t li = (size_t)(bbA * 4 + h) * 4096 + spA;
            float s = lb[li];
            for (int j = 1; j < np; j++) s += lb[(size_t)j * LSTRIDE + li];
            invh[h] = 1.f / s;
        }
    }

    // ---- stage A: attention out-proj + xt residual -> av (LDS bf16) ----
    float4_ acc[4];
#pragma unroll
    for (int nb = 0; nb < 4; nb++) {
        float bvv = bo[n0 + nb * 16 + l15];
        acc[nb] = {bvv, bvv, bvv, bvv};
    }
    for (int kc = 0; kc < 8; kc++) {
        int h = kc >> 1;
        int off = (kc & 1) * 32 + quad * 8;
        size_t obase = ((size_t)(bbA * 4 + h) * 4096 + spA) * 64 + off;
        short8 a;
        if (np) {
            short8 a0v = *(const short8*)(O0 + obase);
            float f[8];
#pragma unroll
            for (int jj = 0; jj < 8; jj++) f[jj] = s2f(a0v[jj]);
            for (int j = 1; j < np; j++) {
                short8 apv = *(const short8*)(Orest + (size_t)(j - 1) * SZO + obase);
#pragma unroll
                for (int jj = 0; jj < 8; jj++) f[jj] += s2f(apv[jj]);
            }
            float iv = invh[h];
            union { short8 s; uint32_t u[4]; } pa;
#pragma unroll
            for (int jj = 0; jj < 4; jj++) {
                float f0 = f[2 * jj] * iv;
                float f1 = f[2 * jj + 1] * iv;
                asm("v_cvt_pk_bf16_f32 %0, %1, %2" : "=v"(pa.u[jj]) : "v"(f0), "v"(f1));
            }
            a = pa.s;
        } else {
            a = *(const short8*)(O0 + obase);
        }
#pragma unroll
        for (int nb = 0; nb < 4; nb++) {
            short8 b = *(const short8*)(woT + (size_t)(n0 + nb * 16 + l15) * 256 + kc * 32 + quad * 8);
            acc[nb] = MFMA16(a, b, acc[nb]);
        }
    }
#pragma unroll
    for (int nb = 0; nb < 4; nb++) {
        int col = n0 + nb * 16 + l15;
#pragma unroll
        for (int r = 0; r < 4; r++) {
            size_t t = (size_t)m0 + quad * 4 + r;
            av[(quad * 4 + r) * 264 + col] = f2bs(acc[nb][r] + s2f(xt[t * 256 + col]));
        }
    }
    __syncthreads();

    // ---- stage B: LN2 stats (16 threads per row, each sums 16 cols) ----
    {
        int row = tid >> 4, sub = tid & 15;
        float sum = 0.f, ss = 0.f;
        short8 v0 = *(const short8*)&av[row * 264 + sub * 16];
        short8 v1 = *(const short8*)&av[row * 264 + sub * 16 + 8];
#pragma unroll
        for (int j = 0; j < 8; j++) {
            float a = s2f(v0[j]), b = s2f(v1[j]);
            sum += a + b; ss += a * a + b * b;
        }
#pragma unroll
        for (int off = 1; off < 16; off <<= 1) {
            sum += __shfl_xor(sum, off);
            ss += __shfl_xor(ss, off);
        }
        if (sub == 0) {
            float mu = sum * (1.f / 256.f);
            float var = ss * (1.f / 256.f) - mu * mu;
            stats[row] = mu;
            stats[16 + row] = rsqrtf(var + 1e-5f);
        }
    }
    __syncthreads();

    // ---- stage C: xn2 = (av - mu) * rs * g2 + be2 (LDS bf16) ----
    {
        int row = tid >> 4, sub = tid & 15;
        float mu = stats[row], rs = stats[16 + row];
#pragma unroll
        for (int j = 0; j < 16; j += 4) {
            int c = sub * 16 + j;
            short4_ rv = *(const short4_*)&av[row * 264 + c];
            short4_ pk;
#pragma unroll
            for (int i = 0; i < 4; i++)
                pk[i] = f2bs((s2f(rv[i]) - mu) * rs * g2[c + i] + be2[c + i]);
            *(short4_*)&x2[row * 264 + c] = pk;
        }
    }
    __syncthreads();

    // ---- stage D: gemm1 + exact GELU -> ff (LDS bf16) ----
#pragma unroll
    for (int nb = 0; nb < 4; nb++) {
        float bvv = b1[n0 + nb * 16 + l15];
        acc[nb] = {bvv, bvv, bvv, bvv};
    }
    for (int kc = 0; kc < 8; kc++) {
        short8 a = *(const short8*)&x2[l15 * 264 + kc * 32 + quad * 8];
#pragma unroll
        for (int nb = 0; nb < 4; nb++) {
            short8 b = *(const short8*)(w1T + (size_t)(n0 + nb * 16 + l15) * 256 + kc * 32 + quad * 8);
            acc[nb] = MFMA16(a, b, acc[nb]);
        }
    }
#pragma unroll
    for (int nb = 0; nb < 4; nb++) {
        int col = n0 + nb * 16 + l15;
#pragma unroll
        for (int r = 0; r < 4; r++) {
            float v = acc[nb][r];
            v = 0.5f * v * (1.f + erff(v * 0.70710678118f));
            ff[(quad * 4 + r) * 264 + col] = f2bs(v);
        }
    }
    __syncthreads();

    // ---- stage E: gemm2 + av residual ----
#pragma unroll
    for (int nb = 0; nb < 4; nb++) {
        float bvv = b2[n0 + nb * 16 + l15];
        acc[nb] = {bvv, bvv, bvv, bvv};
    }
    for (int kc = 0; kc < 8; kc++) {
        short8 a = *(const short8*)&ff[l15 * 264 + kc * 32 + quad * 8];
#pragma unroll
        for (int nb = 0; nb < 4; nb++) {
            short8 b = *(const short8*)(w2T + (size_t)(n0 + nb * 16 + l15) * 256 + kc * 32 + quad * 8);
            acc[nb] = MFMA16(a, b, acc[nb]);
        }
    }
    float vout[4][4];
#pragma unroll
    for (int nb = 0; nb < 4; nb++) {
        int col = n0 + nb * 16 + l15;
#pragma unroll
        for (int r = 0; r < 4; r++)
            vout[nb][r] = acc[nb][r] + s2f(av[(quad * 4 + r) * 264 + col]);
    }
    __syncthreads();   // all reads of av/x2/ff complete before T alias writes

    // wave-private fp32 transpose -> coalesced [b][c][sp] stores
    float* tw = T + w * 1040;
#pragma unroll
    for (int nb = 0; nb < 4; nb++)
#pragma unroll
        for (int r = 0; r < 4; r++)
            tw[(quad * 4 + r) * 65 + nb * 16 + l15] = vout[nb][r];

    int bb = m0 >> 12;
    int spb = m0 & 4095;
    float* dst = outf + ((size_t)bb * 256 + n0 + lane) * SEQ + spb;
#pragma unroll
    for (int j = 0; j < 16; j += 4) {
        float4_ pk = {tw[(j + 0) * 65 + lane], tw[(j + 1) * 65 + lane],
                      tw[(j + 2) * 65 + lane], tw[(j + 3) * 65 + lane]};
        *(float4_*)(dst + j) = pk;
    }
}

// ---------------------------------------------------------------- launch ----
// Chain: repack -> ln1qkv (fused) -> flash -> [combine] -> mlp.
// ROUND-14 CHANGE: nz=4 dropped. Flash duration is nz-invariant (round-3
// measurement), but nz=4 costs 16 MB extra partial writes + 16 MB extra mlp
// reads + 4-way stage-A adds for nothing. Prefer nz=2 FUSED (ws >= 41 MB,
// proven: 49.5 MB layout ran in rounds 3-13). Tiers:
//   nz=2 fused (ws >= 41 MB) / nz=2 split (>= 33) / nz=1.
extern "C" void kernel_launch(void* const* d_in, const int* in_sizes, int n_in,
                              void* d_out, int out_size, void* d_ws, size_t ws_size,
                              hipStream_t stream)
{
    const float* x     = (const float*)d_in[0];
    const float* ln1_g = (const float*)d_in[1];
    const float* ln1_b = (const float*)d_in[2];
    const float* wq    = (const float*)d_in[3];
    const float* bq    = (const float*)d_in[4];
    const float* wk    = (const float*)d_in[5];
    const float* bk    = (const float*)d_in[6];
    const float* wv    = (const float*)d_in[7];
    const float* bv    = (const float*)d_in[8];
    const float* wo    = (const float*)d_in[9];
    const float* bo    = (const float*)d_in[10];
    const float* ln2_g = (const float*)d_in[11];
    const float* ln2_b = (const float*)d_in[12];
    const float* w1    = (const float*)d_in[13];
    const float* b1    = (const float*)d_in[14];
    const float* w2    = (const float*)d_in[15];
    const float* b2    = (const float*)d_in[16];

    char* ws = (char*)d_ws;
    const size_t SZ_BF = (size_t)TOK * 256 * 2;  // 8 MB

    short* wqT = (short*)(ws + 0);
    short* wkT = (short*)(ws + 8192);
    short* wvT = (short*)(ws + 16384);
    short* woT = (short*)(ws + 24576);
    short* w1T = (short*)(ws + 155648);
    short* w2T = (short*)(ws + 286720);
    char* base = ws + 524288;

    short* xt  = (short*)(base);
    short* kbuf= (short*)(base + SZ_BF);
    short* vtb = (short*)(base + 2 * SZ_BF);

    const size_t need2_fb = 524288 + 3 * SZ_BF + 524288 + SZ_BF;      // 33.0 MB
    const size_t need2_fu = need2_fb + SZ_BF;                          // 41.0 MB

    int nz, fuse;
    if (ws_size >= need2_fu)      { nz = 2; fuse = 1; }
    else if (ws_size >= need2_fb) { nz = 2; fuse = 0; }
    else                          { nz = 1; fuse = 0; }

    float* lbase = (float*)(base + 3 * SZ_BF);              // 2 x 256 KB
    short* Orest = (short*)(base + 3 * SZ_BF + 524288);     // O1
    short* O0w   = Orest + SZO;                             // fused only

    short* qb  = (short*)d_out;                      // lower 8 MB
    short* upper = (short*)((char*)d_out + SZ_BF);   // upper 8 MB (O0 in split)
    short* O0  = fuse ? O0w : upper;                 // partial O (grp 0)
    short* Onrm= vtb;                                // normalized O (fallback)

    repack_kernel<<<816, 256, 0, stream>>>(wq, wk, wv, wo, w1, w2,
                                           wqT, wkT, wvT, woT, w1T, w2T);
    ln1qkv_kernel<<<TOK / 64, 512, 0, stream>>>(x, ln1_g, ln1_b,
                                                wqT, wkT, wvT, bq, bk, bv,
                                                xt, qb, kbuf, vtb);
    flash_kernel<<<dim3(32, 16, nz), 256, 0, stream>>>(qb, kbuf, vtb, O0, Orest, lbase);
    if (fuse) {
        mlp_kernel<<<TOK / 16, 256, 0, stream>>>(O0, Orest, lbase, nz,
                                                 woT, w1T, w2T, bo, b1, b2,
                                                 ln2_g, ln2_b, xt, (float*)d_out);
    } else {
        combine_kernel<<<4096, 256, 0, stream>>>(O0, Orest, lbase, Onrm, nz);
        mlp_kernel<<<TOK / 16, 256, 0, stream>>>(Onrm, Orest, lbase, 0,
                                                 woT, w1T, w2T, bo, b1, b2,
                                                 ln2_g, ln2_b, xt, (float*)d_out);
    }
}

// Round 15
// 251.282 us; speedup vs baseline: 1.0430x; 1.0038x over previous
//
#include <hip/hip_runtime.h>
#include <hip/hip_bf16.h>
#include <cstdint>

typedef __attribute__((ext_vector_type(8))) short short8;
typedef __attribute__((ext_vector_type(4))) short short4_;
typedef __attribute__((ext_vector_type(4))) float float4_;
typedef __attribute__((ext_vector_type(16))) float f32x16;

#define MFMA16(a,b,c)  __builtin_amdgcn_mfma_f32_16x16x32_bf16(a,b,c,0,0,0)
#define MFMA32(a,b,c)  __builtin_amdgcn_mfma_f32_32x32x16_bf16(a,b,c,0,0,0)
#define EXP2(x) __builtin_amdgcn_exp2f(x)

// fast bf16 RNE: bit-identical to __float2bfloat16 for all non-NaN inputs.
__device__ __forceinline__ short f2bs(float f) {
    union { float f; uint32_t u; } c;
    c.f = f;
    c.u += 0x7FFF + ((c.u >> 16) & 1);
    return (short)(c.u >> 16);
}
__device__ __forceinline__ float s2f(short s) {
    union { uint32_t u; float f; } c;
    c.u = ((uint32_t)(uint16_t)s) << 16;
    return c.f;
}

static const int EMB = 256;
static const int SEQ = 4096;   // 64*64 spatial
static const int TOK = 16384;  // BS * SEQ

static const size_t SZO = 4194304;   // shorts per O-partial (8 MB)
static const size_t LSTRIDE = 65536; // floats per l-partial (256 KB)

// Attention scale folded into wq/bq: (1/8) * log2(e) -> softmax in exp2 domain.
#define QSCALE 0.18033688011112042f

// ---------------------------------------------------------------- repack ----
__global__ __launch_bounds__(256) void repack_kernel(
    const float* wq, const float* wk, const float* wv,
    const float* wo, const float* w1, const float* w2,
    short* wqT, short* wkT, short* wvT, short* woT, short* w1T, short* w2T)
{
    int idx = blockIdx.x * 256 + threadIdx.x;
    if (idx < 3 * 4096) {
        int m = idx / 4096, r = idx % 4096;
        int n = r / 64, k = r % 64;
        const float* src = (m == 0) ? wq : (m == 1) ? wk : wv;
        short* dst = (m == 0) ? wqT : (m == 1) ? wkT : wvT;
        float v = src[k * 64 + n];
        if (m == 0) v *= QSCALE;
        dst[n * 64 + k] = f2bs(v);
    } else {
        int idx2 = idx - 3 * 4096;
        if (idx2 < 3 * 65536) {
            int m = idx2 / 65536, r = idx2 % 65536;
            int n = r / 256, k = r % 256;
            const float* src = (m == 0) ? wo : (m == 1) ? w1 : w2;
            short* dst = (m == 0) ? woT : (m == 1) ? w1T : w2T;
            dst[n * 256 + k] = f2bs(src[k * 256 + n]);
        }
    }
}

// ---------------------------------------------------------------- ln1qkv ----
// v2 (verbatim — round-11/13/14 best): 512-thread / 8-wave.
// LN phase = 64 tokens x 8 channel-parts (v[32]/thread, single pass);
// projection phase splits each 16-token tile across a WAVE PAIR — even wave:
// full q + V^T nb{0,1}; odd wave: full k + V^T nb{2,3}.
__global__ __launch_bounds__(512, 2) void ln1qkv_kernel(
    const float* x, const float* g, const float* bta,
    const short* wqT, const short* wkT, const short* wvT,
    const float* bq, const float* bk, const float* bv,
    short* xt, short* qo, short* ko, short* vto)
{
    __shared__ short xn_lds[64 * 264];          // 33.8 KB
    __shared__ float redS[8][64], redQ[8][64];  // 4 KB

    int tid = threadIdx.x;
    int l = tid & 63;          // token lane
    int cp = tid >> 6;         // channel part 0..7 (32 channels each)
    int t = blockIdx.x * 64 + l;
    int b = t >> 12, sp = t & 4095;
    const float* xb = x + (size_t)b * EMB * SEQ + (size_t)(cp * 32) * SEQ + sp;

    // ---- phase 1: LN ----
    float v[32];
#pragma unroll
    for (int j = 0; j < 32; j++) v[j] = xb[(size_t)j * SEQ];
    float sum = 0.f, ss = 0.f;
#pragma unroll
    for (int j = 0; j < 32; j++) { sum += v[j]; ss += v[j] * v[j]; }
    redS[cp][l] = sum;
    redQ[cp][l] = ss;
    __syncthreads();
    float S = 0.f, Q = 0.f;
#pragma unroll
    for (int p = 0; p < 8; p++) { S += redS[p][l]; Q += redQ[p][l]; }
    float mu = S * (1.f / 256.f);
    float var = Q * (1.f / 256.f) - mu * mu;
    float rs = rsqrtf(var + 1e-5f);

    short* xtr = xt + (size_t)t * 256 + cp * 32;
    short* xnr = xn_lds + l * 264 + cp * 32;
#pragma unroll
    for (int c = 0; c < 32; c += 8) {
        short8 ra, na;
#pragma unroll
        for (int j = 0; j < 8; j++) {
            float vv = v[c + j];
            ra[j] = f2bs(vv);
            na[j] = f2bs((vv - mu) * rs * g[cp * 32 + c + j] + bta[cp * 32 + c + j]);
        }
        *(short8*)(xtr + c) = ra;
        *(short8*)(xnr + c) = na;
    }
    __syncthreads();

    // ---- phase 2: projections (wave pair per 16-token tile) ----
    int w = tid >> 6;          // wave 0..7
    int lane = tid & 63, quad = lane >> 4, l15 = lane & 15;
    int tt = w >> 1;           // token tile 0..3
    int odd = w & 1;
    int m0 = blockIdx.x * 64 + tt * 16;
    int row = m0 + l15;
    int bb = row >> 12;

    const short* arow = xn_lds + (tt * 16 + l15) * 264;
    short8 a0[4], a1[4];
#pragma unroll
    for (int h = 0; h < 4; h++) {
        a0[h] = *(const short8*)(arow + h * 64 + quad * 8);
        a1[h] = *(const short8*)(arow + h * 64 + 32 + quad * 8);
    }

    // q (even wave) or k (odd wave), full nb 0..3
    {
        const short* WT = odd ? wkT : wqT;
        const float* bias = odd ? bk : bq;
        float bscale = odd ? 1.f : QSCALE;
        short* dst = odd ? ko : qo;
        int s0 = (m0 & 4095) + quad * 4;
#pragma unroll
        for (int nb = 0; nb < 4; nb++) {
            int col = nb * 16 + l15;
            short8 b0 = *(const short8*)(WT + col * 64 + quad * 8);
            short8 b1 = *(const short8*)(WT + col * 64 + 32 + quad * 8);
            float bvv = bias[col] * bscale;
#pragma unroll
            for (int h = 0; h < 4; h++) {
                float4_ acc = {bvv, bvv, bvv, bvv};
                acc = MFMA16(a0[h], b0, acc);
                acc = MFMA16(a1[h], b1, acc);
                size_t headbase = (size_t)(bb * 4 + h) * SEQ;
#pragma unroll
                for (int r = 0; r < 4; r++)
                    dst[(headbase + s0 + r) * 64 + col] = f2bs(acc[r]);
            }
        }
    }

    // V^T half: even wave nb{0,1}, odd wave nb{2,3}
    {
        int sp0 = m0 & 4095;
#pragma unroll
        for (int nbi = 0; nbi < 2; nbi++) {
            int nb = odd * 2 + nbi;
            int colw = nb * 16 + l15;
            short8 b0 = *(const short8*)(wvT + colw * 64 + quad * 8);
            short8 b1 = *(const short8*)(wvT + colw * 64 + 32 + quad * 8);
            float4_ binit;
#pragma unroll
            for (int r = 0; r < 4; r++) binit[r] = bv[nb * 16 + quad * 4 + r];
#pragma unroll
            for (int h = 0; h < 4; h++) {
                float4_ acc = binit;
                acc = MFMA16(b0, a0[h], acc);   // A=weight rows (d), B=xn rows (token)
                acc = MFMA16(b1, a1[h], acc);
                size_t dbase = ((size_t)(bb * 4 + h) * 64 + nb * 16 + quad * 4) * SEQ;
#pragma unroll
                for (int r = 0; r < 4; r++)
                    vto[dbase + (size_t)r * SEQ + sp0 + l15] = f2bs(acc[r]);
            }
        }
    }
}

// ----------------------------------------------------------------- flash ----
// v15 = v14 math + BK=128 stages (two 64-row k-tiles per stage) -> barrier
// pairs per block HALVE (32 -> 16 at nz=2) with the proven double-barrier
// skeleton unchanged. The 32-row sub-chunks are processed in the SAME
// sequential order as v14, so accumulation is bit-identical. Layouts:
// K_lds[128][64] (tile1 rows at +64; s(row) invariant under +64);
// V_lds[64][128] (token chunk j at slot (j&8)|((j&7)^s(row)); tile1 = +64).
// Prefetch doubles to 8 loads (+16 VGPR; live ~110 <= 128 budget).
// Round-9's dbuf failure changed the sync skeleton; this keeps it.
__global__ __attribute__((amdgpu_flat_work_group_size(256, 256),
                          amdgpu_waves_per_eu(2, 4)))
void flash_kernel(
    const short* q, const short* k, const short* vt,
    short* O0, short* Orest, float* lbase)
{
    __shared__ short K_lds[128 * 64];   // 16 KB: [krow 0..127][d 0..63]
    __shared__ short V_lds[64 * 128];   // 16 KB: [d 0..63][token 0..127]

    int tid = threadIdx.x;
    int w = tid >> 6, lane = tid & 63;
    int l31 = lane & 31, hh = lane >> 5;
    int qt = blockIdx.x, bh = blockIdx.y, grp = blockIdx.z;
    int span = 64 / gridDim.z;          // 64-row k-tiles per block (even)
    int nst = span >> 1;                // 128-row stages

    const short* qb = q + (size_t)bh * SEQ * 64;
    const short* kb = k + (size_t)bh * SEQ * 64 + (size_t)grp * span * 64 * 64;
    const short* vb = vt + (size_t)bh * 64 * SEQ + grp * span * 64;

    int qrow = qt * 128 + w * 32 + l31;
    // Q B-fragments: B[n=q=l31][k(d) = kb4*16 + hh*8 + j]
    short8 qf[4];
#pragma unroll
    for (int kb4 = 0; kb4 < 4; kb4++)
        qf[kb4] = *(const short8*)(qb + (size_t)qrow * 64 + kb4 * 16 + hh * 8);

    f32x16 oacc[2];   // O^T[d = td*32 + (reg&3)+8*(reg>>2)+4*hh][q = l31]
#pragma unroll
    for (int td = 0; td < 2; td++)
#pragma unroll
        for (int i = 0; i < 16; i++) oacc[td][i] = 0.f;
    float li = 0.f;

    int srow = tid >> 2;          // 0..63
    int c0 = tid & 3;             // chunk (16B units)
    // write-balanced swizzle: s(row) = (row&7) ^ ((row&1)<<2)
    int sw = (srow & 7) ^ ((srow & 1) << 2);
    int rw = (l31 & 7) ^ ((l31 & 1) << 2);

    int dcA = (c0 ^ sw) << 3;
    int dcB = ((c0 + 4) ^ sw) << 3;

    // prologue: stage stage-0 (k-rows 0..127) into registers
    short8 kr0 = *(const short8*)(kb + (size_t)srow * 64 + c0 * 8);
    short8 kr1 = *(const short8*)(kb + (size_t)srow * 64 + (c0 + 4) * 8);
    short8 kr2 = *(const short8*)(kb + (size_t)(64 + srow) * 64 + c0 * 8);
    short8 kr3 = *(const short8*)(kb + (size_t)(64 + srow) * 64 + (c0 + 4) * 8);
    short8 vr0 = *(const short8*)(vb + (size_t)srow * SEQ + c0 * 8);
    short8 vr1 = *(const short8*)(vb + (size_t)srow * SEQ + (c0 + 4) * 8);
    short8 vr2 = *(const short8*)(vb + (size_t)srow * SEQ + 64 + c0 * 8);
    short8 vr3 = *(const short8*)(vb + (size_t)srow * SEQ + 64 + (c0 + 4) * 8);

    for (int st = 0; st < nst; st++) {
        __syncthreads();          // prev-stage LDS reads done
        *(short8*)&K_lds[srow * 64 + dcA] = kr0;
        *(short8*)&K_lds[srow * 64 + dcB] = kr1;
        *(short8*)&K_lds[(64 + srow) * 64 + dcA] = kr2;
        *(short8*)&K_lds[(64 + srow) * 64 + dcB] = kr3;
        *(short8*)&V_lds[srow * 128 + dcA] = vr0;
        *(short8*)&V_lds[srow * 128 + dcB] = vr1;
        *(short8*)&V_lds[srow * 128 + 64 + dcA] = vr2;   // token chunk | 8
        *(short8*)&V_lds[srow * 128 + 64 + dcB] = vr3;
        if (st + 1 < nst) {       // prefetch next stage; in flight across barrier
            size_t ko = (size_t)((st + 1) * 128 + srow) * 64;
            kr0 = *(const short8*)(kb + ko + c0 * 8);
            kr1 = *(const short8*)(kb + ko + (c0 + 4) * 8);
            kr2 = *(const short8*)(kb + ko + 64 * 64 + c0 * 8);
            kr3 = *(const short8*)(kb + ko + 64 * 64 + (c0 + 4) * 8);
            size_t vo = (size_t)srow * SEQ + (st + 1) * 128;
            vr0 = *(const short8*)(vb + vo + c0 * 8);
            vr1 = *(const short8*)(vb + vo + (c0 + 4) * 8);
            vr2 = *(const short8*)(vb + vo + 64 + c0 * 8);
            vr3 = *(const short8*)(vb + vo + 64 + (c0 + 4) * 8);
        }
        asm volatile("s_waitcnt lgkmcnt(0)" ::: "memory");  // my ds_writes done
        __builtin_amdgcn_s_barrier();                       // no vmcnt(0) drain
        asm volatile("" ::: "memory");

#pragma unroll
        for (int t = 0; t < 4; t++) {
            // ---- QK^T: S[kcol = t*32 + ...][q], 4x MFMA 32x32x16 ----
            f32x16 acc;
#pragma unroll
            for (int i = 0; i < 16; i++) acc[i] = 0.f;
#pragma unroll
            for (int kb4 = 0; kb4 < 4; kb4++) {
                short8 ka = *(const short8*)&K_lds[(t * 32 + l31) * 64 +
                                                   (((kb4 * 2 + hh) ^ rw) << 3)];
                acc = MFMA32(ka, qf[kb4], acc);
            }
            // ---- exp2 (in place) + row-sum (q is lane-local) ----
#pragma unroll
            for (int i = 0; i < 16; i++) acc[i] = EXP2(acc[i]);
            li += ((acc[0] + acc[1]) + (acc[2] + acc[3]))
                + ((acc[4] + acc[5]) + (acc[6] + acc[7]))
                + ((acc[8] + acc[9]) + (acc[10] + acc[11]))
                + ((acc[12] + acc[13]) + (acc[14] + acc[15]));
            // ---- pack P -> PV B-frags via cvt_pk + permlane32_swap ----
            short8 wf[2];
#pragma unroll
            for (int kbl = 0; kbl < 2; kbl++) {
                uint32_t A0, A1, B0, B1;
                asm("v_cvt_pk_bf16_f32 %0, %1, %2" : "=v"(A0)
                    : "v"(acc[kbl * 8 + 0]), "v"(acc[kbl * 8 + 1]));
                asm("v_cvt_pk_bf16_f32 %0, %1, %2" : "=v"(A1)
                    : "v"(acc[kbl * 8 + 2]), "v"(acc[kbl * 8 + 3]));
                asm("v_cvt_pk_bf16_f32 %0, %1, %2" : "=v"(B0)
                    : "v"(acc[kbl * 8 + 4]), "v"(acc[kbl * 8 + 5]));
                asm("v_cvt_pk_bf16_f32 %0, %1, %2" : "=v"(B1)
                    : "v"(acc[kbl * 8 + 6]), "v"(acc[kbl * 8 + 7]));
                // after swap: A = [A_lo|B_lo] (= w0/w1), B = [A_hi|B_hi] (= w2/w3)
                asm("v_permlane32_swap_b32 %0, %1" : "+v"(A0), "+v"(B0));
                asm("v_permlane32_swap_b32 %0, %1" : "+v"(A1), "+v"(B1));
                union { short8 s; uint32_t u[4]; } pw;
                pw.u[0] = A0; pw.u[1] = A1; pw.u[2] = B0; pw.u[3] = B1;
                wf[kbl] = pw.s;
            }
            // ---- PV: O^T += V^T-frag x P-frag, 4x MFMA 32x32x16 ----
            __builtin_amdgcn_s_setprio(1);
#pragma unroll
            for (int kbl = 0; kbl < 2; kbl++) {
                int kc = (t * 2 + kbl) * 2 + hh;              // token chunk 0..15
                int kcs = (kc & 8) | ((kc & 7) ^ rw);          // swizzled slot
#pragma unroll
                for (int td = 0; td < 2; td++) {
                    short8 va = *(const short8*)&V_lds[(td * 32 + l31) * 128 +
                                                       (kcs << 3)];
                    oacc[td] = MFMA32(va, wf[kbl], oacc[td]);
                }
            }
            __builtin_amdgcn_s_setprio(0);
        }
    }

    li += __shfl_xor(li, 32);

    short* Op = grp ? (Orest + (size_t)(grp - 1) * SZO) : O0;
    float* lp = lbase + (size_t)grp * LSTRIDE;
    if (hh == 0) lp[bh * 4096 + qrow] = li;

    size_t ob = ((size_t)bh * 4096 + qrow) * 64;
#pragma unroll
    for (int td = 0; td < 2; td++)
#pragma unroll
        for (int g = 0; g < 4; g++) {
            short4_ pk;
#pragma unroll
            for (int r = 0; r < 4; r++) pk[r] = f2bs(oacc[td][g * 4 + r]);
            *(short4_*)(Op + ob + td * 32 + g * 8 + hh * 4) = pk;
        }
}

// --------------------------------------------------------------- combine ----
// Fallback path only: out = (sum of np partials) / (sum of np l's).
__global__ __launch_bounds__(256) void combine_kernel(
    const short* O0, const short* Orest, const float* lb,
    short* Oout, int np)
{
    int g = blockIdx.x * 256 + threadIdx.x;     // short4 units, 1048576 total
    int qi = g >> 4;
    short4_ a = *(const short4_*)(O0 + (size_t)g * 4);
    float l = lb[qi];
    float4_ acc = {s2f(a[0]), s2f(a[1]), s2f(a[2]), s2f(a[3])};
    for (int j = 1; j < np; j++) {
        short4_ b = *(const short4_*)(Orest + (size_t)(j - 1) * SZO + (size_t)g * 4);
        l += lb[(size_t)j * LSTRIDE + qi];
#pragma unroll
        for (int jj = 0; jj < 4; jj++) acc[jj] += s2f(b[jj]);
    }
    float inv = 1.f / l;
    short4_ pk;
#pragma unroll
    for (int j = 0; j < 4; j++) pk[j] = f2bs(acc[j] * inv);
    *(short4_*)(Oout + (size_t)g * 4) = pk;
}

// ------------------------------------------------------------------- mlp ----
// (verbatim — passing) Fused back half with combine folded into stage A.
__global__ __launch_bounds__(256) void mlp_kernel(
    const short* O0, const short* Orest, const float* lb, int np,
    const short* woT, const short* w1T, const short* w2T,
    const float* bo, const float* b1, const float* b2,
    const float* g2, const float* be2,
    const short* xt, float* outf)
{
    __shared__ __align__(16) char smem[3 * 8448 + 128];
    short* av = (short*)smem;                   // [16][264] bf16
    short* x2 = (short*)(smem + 8448);          // [16][264] bf16
    short* ff = (short*)(smem + 16896);         // [16][264] bf16
    float* stats = (float*)(smem + 25344);      // mu[16], rs[16]
    float* T = (float*)smem;                    // alias av|x2 (16.6 KB <= 16.9)

    int tid = threadIdx.x;
    int w = tid >> 6, lane = tid & 63, quad = lane >> 4, l15 = lane & 15;
    int m0 = blockIdx.x * 16;
    int n0 = w * 64;
    int arow = m0 + l15;
    int bbA = arow >> 12, spA = arow & 4095;

    // per-(head,token) normalizers (loop-invariant, small cached loads)
    float invh[4];
    if (np) {
#pragma unroll
        for (int h = 0; h < 4; h++) {
            size_t li = (size_t)(bbA * 4 + h) * 4096 + spA;
            float s = lb[li];
            for (int j = 1; j < np; j++) s += lb[(size_t)j * LSTRIDE + li];
            invh[h] = 1.f / s;
        }
    }

    // ---- stage A: attention out-proj + xt residual -> av (LDS bf16) ----
    float4_ acc[4];
#pragma unroll
    for (int nb = 0; nb < 4; nb++) {
        float bvv = bo[n0 + nb * 16 + l15];
        acc[nb] = {bvv, bvv, bvv, bvv};
    }
    for (int kc = 0; kc < 8; kc++) {
        int h = kc >> 1;
        int off = (kc & 1) * 32 + quad * 8;
        size_t obase = ((size_t)(bbA * 4 + h) * 4096 + spA) * 64 + off;
        short8 a;
        if (np) {
            short8 a0v = *(const short8*)(O0 + obase);
            float f[8];
#pragma unroll
            for (int jj = 0; jj < 8; jj++) f[jj] = s2f(a0v[jj]);
            for (int j = 1; j < np; j++) {
                short8 apv = *(const short8*)(Orest + (size_t)(j - 1) * SZO + obase);
#pragma unroll
                for (int jj = 0; jj < 8; jj++) f[jj] += s2f(apv[jj]);
            }
            float iv = invh[h];
            union { short8 s; uint32_t u[4]; } pa;
#pragma unroll
            for (int jj = 0; jj < 4; jj++) {
                float f0 = f[2 * jj] * iv;
                float f1 = f[2 * jj + 1] * iv;
                asm("v_cvt_pk_bf16_f32 %0, %1, %2" : "=v"(pa.u[jj]) : "v"(f0), "v"(f1));
            }
            a = pa.s;
        } else {
            a = *(const short8*)(O0 + obase);
        }
#pragma unroll
        for (int nb = 0; nb < 4; nb++) {
            short8 b = *(const short8*)(woT + (size_t)(n0 + nb * 16 + l15) * 256 + kc * 32 + quad * 8);
            acc[nb] = MFMA16(a, b, acc[nb]);
        }
    }
#pragma unroll
    for (int nb = 0; nb < 4; nb++) {
        int col = n0 + nb * 16 + l15;
#pragma unroll
        for (int r = 0; r < 4; r++) {
            size_t t = (size_t)m0 + quad * 4 + r;
            av[(quad * 4 + r) * 264 + col] = f2bs(acc[nb][r] + s2f(xt[t * 256 + col]));
        }
    }
    __syncthreads();

    // ---- stage B: LN2 stats (16 threads per row, each sums 16 cols) ----
    {
        int row = tid >> 4, sub = tid & 15;
        float sum = 0.f, ss = 0.f;
        short8 v0 = *(const short8*)&av[row * 264 + sub * 16];
        short8 v1 = *(const short8*)&av[row * 264 + sub * 16 + 8];
#pragma unroll
        for (int j = 0; j < 8; j++) {
            float a = s2f(v0[j]), b = s2f(v1[j]);
            sum += a + b; ss += a * a + b * b;
        }
#pragma unroll
        for (int off = 1; off < 16; off <<= 1) {
            sum += __shfl_xor(sum, off);
            ss += __shfl_xor(ss, off);
        }
        if (sub == 0) {
            float mu = sum * (1.f / 256.f);
            float var = ss * (1.f / 256.f) - mu * mu;
            stats[row] = mu;
            stats[16 + row] = rsqrtf(var + 1e-5f);
        }
    }
    __syncthreads();

    // ---- stage C: xn2 = (av - mu) * rs * g2 + be2 (LDS bf16) ----
    {
        int row = tid >> 4, sub = tid & 15;
        float mu = stats[row], rs = stats[16 + row];
#pragma unroll
        for (int j = 0; j < 16; j += 4) {
            int c = sub * 16 + j;
            short4_ rv = *(const short4_*)&av[row * 264 + c];
            short4_ pk;
#pragma unroll
            for (int i = 0; i < 4; i++)
                pk[i] = f2bs((s2f(rv[i]) - mu) * rs * g2[c + i] + be2[c + i]);
            *(short4_*)&x2[row * 264 + c] = pk;
        }
    }
    __syncthreads();

    // ---- stage D: gemm1 + exact GELU -> ff (LDS bf16) ----
#pragma unroll
    for (int nb = 0; nb < 4; nb++) {
        float bvv = b1[n0 + nb * 16 + l15];
        acc[nb] = {bvv, bvv, bvv, bvv};
    }
    for (int kc = 0; kc < 8; kc++) {
        short8 a = *(const short8*)&x2[l15 * 264 + kc * 32 + quad * 8];
#pragma unroll
        for (int nb = 0; nb < 4; nb++) {
            short8 b = *(const short8*)(w1T + (size_t)(n0 + nb * 16 + l15) * 256 + kc * 32 + quad * 8);
            acc[nb] = MFMA16(a, b, acc[nb]);
        }
    }
#pragma unroll
    for (int nb = 0; nb < 4; nb++) {
        int col = n0 + nb * 16 + l15;
#pragma unroll
        for (int r = 0; r < 4; r++) {
            float v = acc[nb][r];
            v = 0.5f * v * (1.f + erff(v * 0.70710678118f));
            ff[(quad * 4 + r) * 264 + col] = f2bs(v);
        }
    }
    __syncthreads();

    // ---- stage E: gemm2 + av residual ----
#pragma unroll
    for (int nb = 0; nb < 4; nb++) {
        float bvv = b2[n0 + nb * 16 + l15];
        acc[nb] = {bvv, bvv, bvv, bvv};
    }
    for (int kc = 0; kc < 8; kc++) {
        short8 a = *(const short8*)&ff[l15 * 264 + kc * 32 + quad * 8];
#pragma unroll
        for (int nb = 0; nb < 4; nb++) {
            short8 b = *(const short8*)(w2T + (size_t)(n0 + nb * 16 + l15) * 256 + kc * 32 + quad * 8);
            acc[nb] = MFMA16(a, b, acc[nb]);
        }
    }
    float vout[4][4];
#pragma unroll
    for (int nb = 0; nb < 4; nb++) {
        int col = n0 + nb * 16 + l15;
#pragma unroll
        for (int r = 0; r < 4; r++)
            vout[nb][r] = acc[nb][r] + s2f(av[(quad * 4 + r) * 264 + col]);
    }
    __syncthreads();   // all reads of av/x2/ff complete before T alias writes

    // wave-private fp32 transpose -> coalesced [b][c][sp] stores
    float* tw = T + w * 1040;
#pragma unroll
    for (int nb = 0; nb < 4; nb++)
#pragma unroll
        for (int r = 0; r < 4; r++)
            tw[(quad * 4 + r) * 65 + nb * 16 + l15] = vout[nb][r];

    int bb = m0 >> 12;
    int spb = m0 & 4095;
    float* dst = outf + ((size_t)bb * 256 + n0 + lane) * SEQ + spb;
#pragma unroll
    for (int j = 0; j < 16; j += 4) {
        float4_ pk = {tw[(j + 0) * 65 + lane], tw[(j + 1) * 65 + lane],
                      tw[(j + 2) * 65 + lane], tw[(j + 3) * 65 + lane]};
        *(float4_*)(dst + j) = pk;
    }
}

// ---------------------------------------------------------------- launch ----
// Chain: repack -> ln1qkv (fused) -> flash (BK=128) -> [combine] -> mlp.
// Tiers: nz=2 fused (ws >= 41 MB) / nz=2 split (>= 33) / nz=1.
extern "C" void kernel_launch(void* const* d_in, const int* in_sizes, int n_in,
                              void* d_out, int out_size, void* d_ws, size_t ws_size,
                              hipStream_t stream)
{
    const float* x     = (const float*)d_in[0];
    const float* ln1_g = (const float*)d_in[1];
    const float* ln1_b = (const float*)d_in[2];
    const float* wq    = (const float*)d_in[3];
    const float* bq    = (const float*)d_in[4];
    const float* wk    = (const float*)d_in[5];
    const float* bk    = (const float*)d_in[6];
    const float* wv    = (const float*)d_in[7];
    const float* bv    = (const float*)d_in[8];
    const float* wo    = (const float*)d_in[9];
    const float* bo    = (const float*)d_in[10];
    const float* ln2_g = (const float*)d_in[11];
    const float* ln2_b = (const float*)d_in[12];
    const float* w1    = (const float*)d_in[13];
    const float* b1    = (const float*)d_in[14];
    const float* w2    = (const float*)d_in[15];
    const float* b2    = (const float*)d_in[16];

    char* ws = (char*)d_ws;
    const size_t SZ_BF = (size_t)TOK * 256 * 2;  // 8 MB

    short* wqT = (short*)(ws + 0);
    short* wkT = (short*)(ws + 8192);
    short* wvT = (short*)(ws + 16384);
    short* woT = (short*)(ws + 24576);
    short* w1T = (short*)(ws + 155648);
    short* w2T = (short*)(ws + 286720);
    char* base = ws + 524288;

    short* xt  = (short*)(base);
    short* kbuf= (short*)(base + SZ_BF);
    short* vtb = (short*)(base + 2 * SZ_BF);

    const size_t need2_fb = 524288 + 3 * SZ_BF + 524288 + SZ_BF;      // 33.0 MB
    const size_t need2_fu = need2_fb + SZ_BF;                          // 41.0 MB

    int nz, fuse;
    if (ws_size >= need2_fu)      { nz = 2; fuse = 1; }
    else if (ws_size >= need2_fb) { nz = 2; fuse = 0; }
    else                          { nz = 1; fuse = 0; }

    float* lbase = (float*)(base + 3 * SZ_BF);              // 2 x 256 KB
    short* Orest = (short*)(base + 3 * SZ_BF + 524288);     // O1
    short* O0w   = Orest + SZO;                             // fused only

    short* qb  = (short*)d_out;                      // lower 8 MB
    short* upper = (short*)((char*)d_out + SZ_BF);   // upper 8 MB (O0 in split)
    short* O0  = fuse ? O0w : upper;                 // partial O (grp 0)
    short* Onrm= vtb;                                // normalized O (fallback)

    repack_kernel<<<816, 256, 0, stream>>>(wq, wk, wv, wo, w1, w2,
                                           wqT, wkT, wvT, woT, w1T, w2T);
    ln1qkv_kernel<<<TOK / 64, 512, 0, stream>>>(x, ln1_g, ln1_b,
                                                wqT, wkT, wvT, bq, bk, bv,
                                                xt, qb, kbuf, vtb);
    flash_kernel<<<dim3(32, 16, nz), 256, 0, stream>>>(qb, kbuf, vtb, O0, Orest, lbase);
    if (fuse) {
        mlp_kernel<<<TOK / 16, 256, 0, stream>>>(O0, Orest, lbase, nz,
                                                 woT, w1T, w2T, bo, b1, b2,
                                                 ln2_g, ln2_b, xt, (float*)d_out);
    } else {
        combine_kernel<<<4096, 256, 0, stream>>>(O0, Orest, lbase, Onrm, nz);
        mlp_kernel<<<TOK / 16, 256, 0, stream>>>(Onrm, Orest, lbase, 0,
                                                 woT, w1T, w2T, bo, b1, b2,
                                                 ln2_g, ln2_b, xt, (float*)d_out);
    }
}

// Round 16
// 251.173 us; speedup vs baseline: 1.0435x; 1.0004x over previous
//
#include <hip/hip_runtime.h>
#include <hip/hip_bf16.h>
#include <cstdint>

typedef __attribute__((ext_vector_type(8))) short short8;
typedef __attribute__((ext_vector_type(4))) short short4_;
typedef __attribute__((ext_vector_type(4))) float float4_;
typedef __attribute__((ext_vector_type(16))) float f32x16;

#define MFMA16(a,b,c)  __builtin_amdgcn_mfma_f32_16x16x32_bf16(a,b,c,0,0,0)
#define MFMA32(a,b,c)  __builtin_amdgcn_mfma_f32_32x32x16_bf16(a,b,c,0,0,0)
#define EXP2(x) __builtin_amdgcn_exp2f(x)

// fast bf16 RNE: bit-identical to __float2bfloat16 for all non-NaN inputs.
__device__ __forceinline__ short f2bs(float f) {
    union { float f; uint32_t u; } c;
    c.f = f;
    c.u += 0x7FFF + ((c.u >> 16) & 1);
    return (short)(c.u >> 16);
}
__device__ __forceinline__ float s2f(short s) {
    union { uint32_t u; float f; } c;
    c.u = ((uint32_t)(uint16_t)s) << 16;
    return c.f;
}

static const int EMB = 256;
static const int SEQ = 4096;   // 64*64 spatial
static const int TOK = 16384;  // BS * SEQ

static const size_t SZO = 4194304;   // shorts per O-partial (8 MB)
static const size_t LSTRIDE = 65536; // floats per l-partial (256 KB)

// Attention scale folded into wq/bq: (1/8) * log2(e) -> softmax in exp2 domain.
#define QSCALE 0.18033688011112042f

// ---------------------------------------------------------------- repack ----
__global__ __launch_bounds__(256) void repack_kernel(
    const float* wq, const float* wk, const float* wv,
    const float* wo, const float* w1, const float* w2,
    short* wqT, short* wkT, short* wvT, short* woT, short* w1T, short* w2T)
{
    int idx = blockIdx.x * 256 + threadIdx.x;
    if (idx < 3 * 4096) {
        int m = idx / 4096, r = idx % 4096;
        int n = r / 64, k = r % 64;
        const float* src = (m == 0) ? wq : (m == 1) ? wk : wv;
        short* dst = (m == 0) ? wqT : (m == 1) ? wkT : wvT;
        float v = src[k * 64 + n];
        if (m == 0) v *= QSCALE;
        dst[n * 64 + k] = f2bs(v);
    } else {
        int idx2 = idx - 3 * 4096;
        if (idx2 < 3 * 65536) {
            int m = idx2 / 65536, r = idx2 % 65536;
            int n = r / 256, k = r % 256;
            const float* src = (m == 0) ? wo : (m == 1) ? w1 : w2;
            short* dst = (m == 0) ? woT : (m == 1) ? w1T : w2T;
            dst[n * 256 + k] = f2bs(src[k * 256 + n]);
        }
    }
}

// ---------------------------------------------------------------- ln1qkv ----
// v2 (verbatim — round-11/13/14/15 best): 512-thread / 8-wave.
__global__ __launch_bounds__(512, 2) void ln1qkv_kernel(
    const float* x, const float* g, const float* bta,
    const short* wqT, const short* wkT, const short* wvT,
    const float* bq, const float* bk, const float* bv,
    short* xt, short* qo, short* ko, short* vto)
{
    __shared__ short xn_lds[64 * 264];          // 33.8 KB
    __shared__ float redS[8][64], redQ[8][64];  // 4 KB

    int tid = threadIdx.x;
    int l = tid & 63;          // token lane
    int cp = tid >> 6;         // channel part 0..7 (32 channels each)
    int t = blockIdx.x * 64 + l;
    int b = t >> 12, sp = t & 4095;
    const float* xb = x + (size_t)b * EMB * SEQ + (size_t)(cp * 32) * SEQ + sp;

    // ---- phase 1: LN ----
    float v[32];
#pragma unroll
    for (int j = 0; j < 32; j++) v[j] = xb[(size_t)j * SEQ];
    float sum = 0.f, ss = 0.f;
#pragma unroll
    for (int j = 0; j < 32; j++) { sum += v[j]; ss += v[j] * v[j]; }
    redS[cp][l] = sum;
    redQ[cp][l] = ss;
    __syncthreads();
    float S = 0.f, Q = 0.f;
#pragma unroll
    for (int p = 0; p < 8; p++) { S += redS[p][l]; Q += redQ[p][l]; }
    float mu = S * (1.f / 256.f);
    float var = Q * (1.f / 256.f) - mu * mu;
    float rs = rsqrtf(var + 1e-5f);

    short* xtr = xt + (size_t)t * 256 + cp * 32;
    short* xnr = xn_lds + l * 264 + cp * 32;
#pragma unroll
    for (int c = 0; c < 32; c += 8) {
        short8 ra, na;
#pragma unroll
        for (int j = 0; j < 8; j++) {
            float vv = v[c + j];
            ra[j] = f2bs(vv);
            na[j] = f2bs((vv - mu) * rs * g[cp * 32 + c + j] + bta[cp * 32 + c + j]);
        }
        *(short8*)(xtr + c) = ra;
        *(short8*)(xnr + c) = na;
    }
    __syncthreads();

    // ---- phase 2: projections (wave pair per 16-token tile) ----
    int w = tid >> 6;          // wave 0..7
    int lane = tid & 63, quad = lane >> 4, l15 = lane & 15;
    int tt = w >> 1;           // token tile 0..3
    int odd = w & 1;
    int m0 = blockIdx.x * 64 + tt * 16;
    int row = m0 + l15;
    int bb = row >> 12;

    const short* arow = xn_lds + (tt * 16 + l15) * 264;
    short8 a0[4], a1[4];
#pragma unroll
    for (int h = 0; h < 4; h++) {
        a0[h] = *(const short8*)(arow + h * 64 + quad * 8);
        a1[h] = *(const short8*)(arow + h * 64 + 32 + quad * 8);
    }

    // q (even wave) or k (odd wave), full nb 0..3
    {
        const short* WT = odd ? wkT : wqT;
        const float* bias = odd ? bk : bq;
        float bscale = odd ? 1.f : QSCALE;
        short* dst = odd ? ko : qo;
        int s0 = (m0 & 4095) + quad * 4;
#pragma unroll
        for (int nb = 0; nb < 4; nb++) {
            int col = nb * 16 + l15;
            short8 b0 = *(const short8*)(WT + col * 64 + quad * 8);
            short8 b1 = *(const short8*)(WT + col * 64 + 32 + quad * 8);
            float bvv = bias[col] * bscale;
#pragma unroll
            for (int h = 0; h < 4; h++) {
                float4_ acc = {bvv, bvv, bvv, bvv};
                acc = MFMA16(a0[h], b0, acc);
                acc = MFMA16(a1[h], b1, acc);
                size_t headbase = (size_t)(bb * 4 + h) * SEQ;
#pragma unroll
                for (int r = 0; r < 4; r++)
                    dst[(headbase + s0 + r) * 64 + col] = f2bs(acc[r]);
            }
        }
    }

    // V^T half: even wave nb{0,1}, odd wave nb{2,3}
    {
        int sp0 = m0 & 4095;
#pragma unroll
        for (int nbi = 0; nbi < 2; nbi++) {
            int nb = odd * 2 + nbi;
            int colw = nb * 16 + l15;
            short8 b0 = *(const short8*)(wvT + colw * 64 + quad * 8);
            short8 b1 = *(const short8*)(wvT + colw * 64 + 32 + quad * 8);
            float4_ binit;
#pragma unroll
            for (int r = 0; r < 4; r++) binit[r] = bv[nb * 16 + quad * 4 + r];
#pragma unroll
            for (int h = 0; h < 4; h++) {
                float4_ acc = binit;
                acc = MFMA16(b0, a0[h], acc);   // A=weight rows (d), B=xn rows (token)
                acc = MFMA16(b1, a1[h], acc);
                size_t dbase = ((size_t)(bb * 4 + h) * 64 + nb * 16 + quad * 4) * SEQ;
#pragma unroll
                for (int r = 0; r < 4; r++)
                    vto[dbase + (size_t)r * SEQ + sp0 + l15] = f2bs(acc[r]);
            }
        }
    }
}

// ----------------------------------------------------------------- flash ----
// v15 (verbatim — passing, ~90.6 us, VGPR 84, no spill): v14 math + BK=128
// stages; 32x32x16 MFMA both GEMMs; write-balanced swizzle; cvt_pk +
// permlane32_swap P redistribution.
__global__ __attribute__((amdgpu_flat_work_group_size(256, 256),
                          amdgpu_waves_per_eu(2, 4)))
void flash_kernel(
    const short* q, const short* k, const short* vt,
    short* O0, short* Orest, float* lbase)
{
    __shared__ short K_lds[128 * 64];   // 16 KB: [krow 0..127][d 0..63]
    __shared__ short V_lds[64 * 128];   // 16 KB: [d 0..63][token 0..127]

    int tid = threadIdx.x;
    int w = tid >> 6, lane = tid & 63;
    int l31 = lane & 31, hh = lane >> 5;
    int qt = blockIdx.x, bh = blockIdx.y, grp = blockIdx.z;
    int span = 64 / gridDim.z;          // 64-row k-tiles per block (even)
    int nst = span >> 1;                // 128-row stages

    const short* qb = q + (size_t)bh * SEQ * 64;
    const short* kb = k + (size_t)bh * SEQ * 64 + (size_t)grp * span * 64 * 64;
    const short* vb = vt + (size_t)bh * 64 * SEQ + grp * span * 64;

    int qrow = qt * 128 + w * 32 + l31;
    // Q B-fragments: B[n=q=l31][k(d) = kb4*16 + hh*8 + j]
    short8 qf[4];
#pragma unroll
    for (int kb4 = 0; kb4 < 4; kb4++)
        qf[kb4] = *(const short8*)(qb + (size_t)qrow * 64 + kb4 * 16 + hh * 8);

    f32x16 oacc[2];   // O^T[d = td*32 + (reg&3)+8*(reg>>2)+4*hh][q = l31]
#pragma unroll
    for (int td = 0; td < 2; td++)
#pragma unroll
        for (int i = 0; i < 16; i++) oacc[td][i] = 0.f;
    float li = 0.f;

    int srow = tid >> 2;          // 0..63
    int c0 = tid & 3;             // chunk (16B units)
    // write-balanced swizzle: s(row) = (row&7) ^ ((row&1)<<2)
    int sw = (srow & 7) ^ ((srow & 1) << 2);
    int rw = (l31 & 7) ^ ((l31 & 1) << 2);

    int dcA = (c0 ^ sw) << 3;
    int dcB = ((c0 + 4) ^ sw) << 3;

    // prologue: stage stage-0 (k-rows 0..127) into registers
    short8 kr0 = *(const short8*)(kb + (size_t)srow * 64 + c0 * 8);
    short8 kr1 = *(const short8*)(kb + (size_t)srow * 64 + (c0 + 4) * 8);
    short8 kr2 = *(const short8*)(kb + (size_t)(64 + srow) * 64 + c0 * 8);
    short8 kr3 = *(const short8*)(kb + (size_t)(64 + srow) * 64 + (c0 + 4) * 8);
    short8 vr0 = *(const short8*)(vb + (size_t)srow * SEQ + c0 * 8);
    short8 vr1 = *(const short8*)(vb + (size_t)srow * SEQ + (c0 + 4) * 8);
    short8 vr2 = *(const short8*)(vb + (size_t)srow * SEQ + 64 + c0 * 8);
    short8 vr3 = *(const short8*)(vb + (size_t)srow * SEQ + 64 + (c0 + 4) * 8);

    for (int st = 0; st < nst; st++) {
        __syncthreads();          // prev-stage LDS reads done
        *(short8*)&K_lds[srow * 64 + dcA] = kr0;
        *(short8*)&K_lds[srow * 64 + dcB] = kr1;
        *(short8*)&K_lds[(64 + srow) * 64 + dcA] = kr2;
        *(short8*)&K_lds[(64 + srow) * 64 + dcB] = kr3;
        *(short8*)&V_lds[srow * 128 + dcA] = vr0;
        *(short8*)&V_lds[srow * 128 + dcB] = vr1;
        *(short8*)&V_lds[srow * 128 + 64 + dcA] = vr2;   // token chunk | 8
        *(short8*)&V_lds[srow * 128 + 64 + dcB] = vr3;
        if (st + 1 < nst) {       // prefetch next stage; in flight across barrier
            size_t ko = (size_t)((st + 1) * 128 + srow) * 64;
            kr0 = *(const short8*)(kb + ko + c0 * 8);
            kr1 = *(const short8*)(kb + ko + (c0 + 4) * 8);
            kr2 = *(const short8*)(kb + ko + 64 * 64 + c0 * 8);
            kr3 = *(const short8*)(kb + ko + 64 * 64 + (c0 + 4) * 8);
            size_t vo = (size_t)srow * SEQ + (st + 1) * 128;
            vr0 = *(const short8*)(vb + vo + c0 * 8);
            vr1 = *(const short8*)(vb + vo + (c0 + 4) * 8);
            vr2 = *(const short8*)(vb + vo + 64 + c0 * 8);
            vr3 = *(const short8*)(vb + vo + 64 + (c0 + 4) * 8);
        }
        asm volatile("s_waitcnt lgkmcnt(0)" ::: "memory");  // my ds_writes done
        __builtin_amdgcn_s_barrier();                       // no vmcnt(0) drain
        asm volatile("" ::: "memory");

#pragma unroll
        for (int t = 0; t < 4; t++) {
            // ---- QK^T: S[kcol = t*32 + ...][q], 4x MFMA 32x32x16 ----
            f32x16 acc;
#pragma unroll
            for (int i = 0; i < 16; i++) acc[i] = 0.f;
#pragma unroll
            for (int kb4 = 0; kb4 < 4; kb4++) {
                short8 ka = *(const short8*)&K_lds[(t * 32 + l31) * 64 +
                                                   (((kb4 * 2 + hh) ^ rw) << 3)];
                acc = MFMA32(ka, qf[kb4], acc);
            }
            // ---- exp2 (in place) + row-sum (q is lane-local) ----
#pragma unroll
            for (int i = 0; i < 16; i++) acc[i] = EXP2(acc[i]);
            li += ((acc[0] + acc[1]) + (acc[2] + acc[3]))
                + ((acc[4] + acc[5]) + (acc[6] + acc[7]))
                + ((acc[8] + acc[9]) + (acc[10] + acc[11]))
                + ((acc[12] + acc[13]) + (acc[14] + acc[15]));
            // ---- pack P -> PV B-frags via cvt_pk + permlane32_swap ----
            short8 wf[2];
#pragma unroll
            for (int kbl = 0; kbl < 2; kbl++) {
                uint32_t A0, A1, B0, B1;
                asm("v_cvt_pk_bf16_f32 %0, %1, %2" : "=v"(A0)
                    : "v"(acc[kbl * 8 + 0]), "v"(acc[kbl * 8 + 1]));
                asm("v_cvt_pk_bf16_f32 %0, %1, %2" : "=v"(A1)
                    : "v"(acc[kbl * 8 + 2]), "v"(acc[kbl * 8 + 3]));
                asm("v_cvt_pk_bf16_f32 %0, %1, %2" : "=v"(B0)
                    : "v"(acc[kbl * 8 + 4]), "v"(acc[kbl * 8 + 5]));
                asm("v_cvt_pk_bf16_f32 %0, %1, %2" : "=v"(B1)
                    : "v"(acc[kbl * 8 + 6]), "v"(acc[kbl * 8 + 7]));
                // after swap: A = [A_lo|B_lo] (= w0/w1), B = [A_hi|B_hi] (= w2/w3)
                asm("v_permlane32_swap_b32 %0, %1" : "+v"(A0), "+v"(B0));
                asm("v_permlane32_swap_b32 %0, %1" : "+v"(A1), "+v"(B1));
                union { short8 s; uint32_t u[4]; } pw;
                pw.u[0] = A0; pw.u[1] = A1; pw.u[2] = B0; pw.u[3] = B1;
                wf[kbl] = pw.s;
            }
            // ---- PV: O^T += V^T-frag x P-frag, 4x MFMA 32x32x16 ----
            __builtin_amdgcn_s_setprio(1);
#pragma unroll
            for (int kbl = 0; kbl < 2; kbl++) {
                int kc = (t * 2 + kbl) * 2 + hh;              // token chunk 0..15
                int kcs = (kc & 8) | ((kc & 7) ^ rw);          // swizzled slot
#pragma unroll
                for (int td = 0; td < 2; td++) {
                    short8 va = *(const short8*)&V_lds[(td * 32 + l31) * 128 +
                                                       (kcs << 3)];
                    oacc[td] = MFMA32(va, wf[kbl], oacc[td]);
                }
            }
            __builtin_amdgcn_s_setprio(0);
        }
    }

    li += __shfl_xor(li, 32);

    short* Op = grp ? (Orest + (size_t)(grp - 1) * SZO) : O0;
    float* lp = lbase + (size_t)grp * LSTRIDE;
    if (hh == 0) lp[bh * 4096 + qrow] = li;

    size_t ob = ((size_t)bh * 4096 + qrow) * 64;
#pragma unroll
    for (int td = 0; td < 2; td++)
#pragma unroll
        for (int g = 0; g < 4; g++) {
            short4_ pk;
#pragma unroll
            for (int r = 0; r < 4; r++) pk[r] = f2bs(oacc[td][g * 4 + r]);
            *(short4_*)(Op + ob + td * 32 + g * 8 + hh * 4) = pk;
        }
}

// --------------------------------------------------------------- combine ----
// Fallback path only: out = (sum of np partials) / (sum of np l's).
__global__ __launch_bounds__(256) void combine_kernel(
    const short* O0, const short* Orest, const float* lb,
    short* Oout, int np)
{
    int g = blockIdx.x * 256 + threadIdx.x;     // short4 units, 1048576 total
    int qi = g >> 4;
    short4_ a = *(const short4_*)(O0 + (size_t)g * 4);
    float l = lb[qi];
    float4_ acc = {s2f(a[0]), s2f(a[1]), s2f(a[2]), s2f(a[3])};
    for (int j = 1; j < np; j++) {
        short4_ b = *(const short4_*)(Orest + (size_t)(j - 1) * SZO + (size_t)g * 4);
        l += lb[(size_t)j * LSTRIDE + qi];
#pragma unroll
        for (int jj = 0; jj < 4; jj++) acc[jj] += s2f(b[jj]);
    }
    float inv = 1.f / l;
    short4_ pk;
#pragma unroll
    for (int j = 0; j < 4; j++) pk[j] = f2bs(acc[j] * inv);
    *(short4_*)(Oout + (size_t)g * 4) = pk;
}

// ------------------------------------------------------------------- mlp ----
// v2: 32-token tiles, 512 threads / 8 waves. Each wave keeps the identical
// 16-token x 64-col workload of v1 (wave = (token-half th = w>>2, col-slice
// n0 = (w&3)*64)), so per-thread arithmetic is bit-identical; weight L2
// re-reads and barrier count PER TOKEN halve; grid 1024 -> 512.
// LDS: av/x2/ff [32][264] bf16 (16.9 KB each) + stats[64] = 50.9 KB
// (3 blocks/CU by LDS >= grid's 2/CU). Transpose alias: T = 8 waves x
// 1040 floats = 33.3 KB <= av+x2 (33.8 KB); ff untouched by T.
__global__ __launch_bounds__(512, 2) void mlp_kernel(
    const short* O0, const short* Orest, const float* lb, int np,
    const short* woT, const short* w1T, const short* w2T,
    const float* bo, const float* b1, const float* b2,
    const float* g2, const float* be2,
    const short* xt, float* outf)
{
    __shared__ __align__(16) char smem[3 * 16896 + 256];
    short* av = (short*)smem;                   // [32][264] bf16
    short* x2 = (short*)(smem + 16896);         // [32][264] bf16
    short* ff = (short*)(smem + 33792);         // [32][264] bf16
    float* stats = (float*)(smem + 50688);      // mu[32], rs[32]
    float* T = (float*)smem;                    // alias av|x2 (33.3 <= 33.8 KB)

    int tid = threadIdx.x;
    int w = tid >> 6, lane = tid & 63, quad = lane >> 4, l15 = lane & 15;
    int m0 = blockIdx.x * 32;
    int th = w >> 2;                // token half 0..1
    int n0 = (w & 3) * 64;          // col slice
    int arow = m0 + th * 16 + l15;
    int bbA = arow >> 12, spA = arow & 4095;

    // per-(head,token) normalizers (loop-invariant, small cached loads)
    float invh[4];
    if (np) {
#pragma unroll
        for (int h = 0; h < 4; h++) {
            size_t li = (size_t)(bbA * 4 + h) * 4096 + spA;
            float s = lb[li];
            for (int j = 1; j < np; j++) s += lb[(size_t)j * LSTRIDE + li];
            invh[h] = 1.f / s;
        }
    }

    // ---- stage A: attention out-proj + xt residual -> av (LDS bf16) ----
    float4_ acc[4];
#pragma unroll
    for (int nb = 0; nb < 4; nb++) {
        float bvv = bo[n0 + nb * 16 + l15];
        acc[nb] = {bvv, bvv, bvv, bvv};
    }
    for (int kc = 0; kc < 8; kc++) {
        int h = kc >> 1;
        int off = (kc & 1) * 32 + quad * 8;
        size_t obase = ((size_t)(bbA * 4 + h) * 4096 + spA) * 64 + off;
        short8 a;
        if (np) {
            short8 a0v = *(const short8*)(O0 + obase);
            float f[8];
#pragma unroll
            for (int jj = 0; jj < 8; jj++) f[jj] = s2f(a0v[jj]);
            for (int j = 1; j < np; j++) {
                short8 apv = *(const short8*)(Orest + (size_t)(j - 1) * SZO + obase);
#pragma unroll
                for (int jj = 0; jj < 8; jj++) f[jj] += s2f(apv[jj]);
            }
            float iv = invh[h];
            union { short8 s; uint32_t u[4]; } pa;
#pragma unroll
            for (int jj = 0; jj < 4; jj++) {
                float f0 = f[2 * jj] * iv;
                float f1 = f[2 * jj + 1] * iv;
                asm("v_cvt_pk_bf16_f32 %0, %1, %2" : "=v"(pa.u[jj]) : "v"(f0), "v"(f1));
            }
            a = pa.s;
        } else {
            a = *(const short8*)(O0 + obase);
        }
#pragma unroll
        for (int nb = 0; nb < 4; nb++) {
            short8 b = *(const short8*)(woT + (size_t)(n0 + nb * 16 + l15) * 256 + kc * 32 + quad * 8);
            acc[nb] = MFMA16(a, b, acc[nb]);
        }
    }
#pragma unroll
    for (int nb = 0; nb < 4; nb++) {
        int col = n0 + nb * 16 + l15;
#pragma unroll
        for (int r = 0; r < 4; r++) {
            size_t t = (size_t)m0 + th * 16 + quad * 4 + r;
            av[(th * 16 + quad * 4 + r) * 264 + col] = f2bs(acc[nb][r] + s2f(xt[t * 256 + col]));
        }
    }
    __syncthreads();

    // ---- stage B: LN2 stats (16 threads per row, 32 rows) ----
    {
        int row = tid >> 4, sub = tid & 15;
        float sum = 0.f, ss = 0.f;
        short8 v0 = *(const short8*)&av[row * 264 + sub * 16];
        short8 v1 = *(const short8*)&av[row * 264 + sub * 16 + 8];
#pragma unroll
        for (int j = 0; j < 8; j++) {
            float a = s2f(v0[j]), b = s2f(v1[j]);
            sum += a + b; ss += a * a + b * b;
        }
#pragma unroll
        for (int off = 1; off < 16; off <<= 1) {
            sum += __shfl_xor(sum, off);
            ss += __shfl_xor(ss, off);
        }
        if (sub == 0) {
            float mu = sum * (1.f / 256.f);
            float var = ss * (1.f / 256.f) - mu * mu;
            stats[row] = mu;
            stats[32 + row] = rsqrtf(var + 1e-5f);
        }
    }
    __syncthreads();

    // ---- stage C: xn2 = (av - mu) * rs * g2 + be2 (LDS bf16) ----
    {
        int row = tid >> 4, sub = tid & 15;
        float mu = stats[row], rs = stats[32 + row];
#pragma unroll
        for (int j = 0; j < 16; j += 4) {
            int c = sub * 16 + j;
            short4_ rv = *(const short4_*)&av[row * 264 + c];
            short4_ pk;
#pragma unroll
            for (int i = 0; i < 4; i++)
                pk[i] = f2bs((s2f(rv[i]) - mu) * rs * g2[c + i] + be2[c + i]);
            *(short4_*)&x2[row * 264 + c] = pk;
        }
    }
    __syncthreads();

    // ---- stage D: gemm1 + exact GELU -> ff (LDS bf16) ----
#pragma unroll
    for (int nb = 0; nb < 4; nb++) {
        float bvv = b1[n0 + nb * 16 + l15];
        acc[nb] = {bvv, bvv, bvv, bvv};
    }
    for (int kc = 0; kc < 8; kc++) {
        short8 a = *(const short8*)&x2[(th * 16 + l15) * 264 + kc * 32 + quad * 8];
#pragma unroll
        for (int nb = 0; nb < 4; nb++) {
            short8 b = *(const short8*)(w1T + (size_t)(n0 + nb * 16 + l15) * 256 + kc * 32 + quad * 8);
            acc[nb] = MFMA16(a, b, acc[nb]);
        }
    }
#pragma unroll
    for (int nb = 0; nb < 4; nb++) {
        int col = n0 + nb * 16 + l15;
#pragma unroll
        for (int r = 0; r < 4; r++) {
            float v = acc[nb][r];
            v = 0.5f * v * (1.f + erff(v * 0.70710678118f));
            ff[(th * 16 + quad * 4 + r) * 264 + col] = f2bs(v);
        }
    }
    __syncthreads();

    // ---- stage E: gemm2 + av residual ----
#pragma unroll
    for (int nb = 0; nb < 4; nb++) {
        float bvv = b2[n0 + nb * 16 + l15];
        acc[nb] = {bvv, bvv, bvv, bvv};
    }
    for (int kc = 0; kc < 8; kc++) {
        short8 a = *(const short8*)&ff[(th * 16 + l15) * 264 + kc * 32 + quad * 8];
#pragma unroll
        for (int nb = 0; nb < 4; nb++) {
            short8 b = *(const short8*)(w2T + (size_t)(n0 + nb * 16 + l15) * 256 + kc * 32 + quad * 8);
            acc[nb] = MFMA16(a, b, acc[nb]);
        }
    }
    float vout[4][4];
#pragma unroll
    for (int nb = 0; nb < 4; nb++) {
        int col = n0 + nb * 16 + l15;
#pragma unroll
        for (int r = 0; r < 4; r++)
            vout[nb][r] = acc[nb][r] + s2f(av[(th * 16 + quad * 4 + r) * 264 + col]);
    }
    __syncthreads();   // all reads of av/x2/ff complete before T alias writes

    // wave-private fp32 transpose -> coalesced [b][c][sp] stores
    float* tw = T + w * 1040;
#pragma unroll
    for (int nb = 0; nb < 4; nb++)
#pragma unroll
        for (int r = 0; r < 4; r++)
            tw[(quad * 4 + r) * 65 + nb * 16 + l15] = vout[nb][r];

    int bb = m0 >> 12;
    int spb = (m0 & 4095) + th * 16;
    float* dst = outf + ((size_t)bb * 256 + n0 + lane) * SEQ + spb;
#pragma unroll
    for (int j = 0; j < 16; j += 4) {
        float4_ pk = {tw[(j + 0) * 65 + lane], tw[(j + 1) * 65 + lane],
                      tw[(j + 2) * 65 + lane], tw[(j + 3) * 65 + lane]};
        *(float4_*)(dst + j) = pk;
    }
}

// ---------------------------------------------------------------- launch ----
// Chain: repack -> ln1qkv (fused) -> flash (BK=128) -> [combine] ->
// mlp (32-token tiles). Tiers: nz=2 fused (ws >= 41 MB) / nz=2 split
// (>= 33) / nz=1.
extern "C" void kernel_launch(void* const* d_in, const int* in_sizes, int n_in,
                              void* d_out, int out_size, void* d_ws, size_t ws_size,
                              hipStream_t stream)
{
    const float* x     = (const float*)d_in[0];
    const float* ln1_g = (const float*)d_in[1];
    const float* ln1_b = (const float*)d_in[2];
    const float* wq    = (const float*)d_in[3];
    const float* bq    = (const float*)d_in[4];
    const float* wk    = (const float*)d_in[5];
    const float* bk    = (const float*)d_in[6];
    const float* wv    = (const float*)d_in[7];
    const float* bv    = (const float*)d_in[8];
    const float* wo    = (const float*)d_in[9];
    const float* bo    = (const float*)d_in[10];
    const float* ln2_g = (const float*)d_in[11];
    const float* ln2_b = (const float*)d_in[12];
    const float* w1    = (const float*)d_in[13];
    const float* b1    = (const float*)d_in[14];
    const float* w2    = (const float*)d_in[15];
    const float* b2    = (const float*)d_in[16];

    char* ws = (char*)d_ws;
    const size_t SZ_BF = (size_t)TOK * 256 * 2;  // 8 MB

    short* wqT = (short*)(ws + 0);
    short* wkT = (short*)(ws + 8192);
    short* wvT = (short*)(ws + 16384);
    short* woT = (short*)(ws + 24576);
    short* w1T = (short*)(ws + 155648);
    short* w2T = (short*)(ws + 286720);
    char* base = ws + 524288;

    short* xt  = (short*)(base);
    short* kbuf= (short*)(base + SZ_BF);
    short* vtb = (short*)(base + 2 * SZ_BF);

    const size_t need2_fb = 524288 + 3 * SZ_BF + 524288 + SZ_BF;      // 33.0 MB
    const size_t need2_fu = need2_fb + SZ_BF;                          // 41.0 MB

    int nz, fuse;
    if (ws_size >= need2_fu)      { nz = 2; fuse = 1; }
    else if (ws_size >= need2_fb) { nz = 2; fuse = 0; }
    else                          { nz = 1; fuse = 0; }

    float* lbase = (float*)(base + 3 * SZ_BF);              // 2 x 256 KB
    short* Orest = (short*)(base + 3 * SZ_BF + 524288);     // O1
    short* O0w   = Orest + SZO;                             // fused only

    short* qb  = (short*)d_out;                      // lower 8 MB
    short* upper = (short*)((char*)d_out + SZ_BF);   // upper 8 MB (O0 in split)
    short* O0  = fuse ? O0w : upper;                 // partial O (grp 0)
    short* Onrm= vtb;                                // normalized O (fallback)

    repack_kernel<<<816, 256, 0, stream>>>(wq, wk, wv, wo, w1, w2,
                                           wqT, wkT, wvT, woT, w1T, w2T);
    ln1qkv_kernel<<<TOK / 64, 512, 0, stream>>>(x, ln1_g, ln1_b,
                                                wqT, wkT, wvT, bq, bk, bv,
                                                xt, qb, kbuf, vtb);
    flash_kernel<<<dim3(32, 16, nz), 256, 0, stream>>>(qb, kbuf, vtb, O0, Orest, lbase);
    if (fuse) {
        mlp_kernel<<<TOK / 32, 512, 0, stream>>>(O0, Orest, lbase, nz,
                                                 woT, w1T, w2T, bo, b1, b2,
                                                 ln2_g, ln2_b, xt, (float*)d_out);
    } else {
        combine_kernel<<<4096, 256, 0, stream>>>(O0, Orest, lbase, Onrm, nz);
        mlp_kernel<<<TOK / 32, 512, 0, stream>>>(Onrm, Orest, lbase, 0,
                                                 woT, w1T, w2T, bo, b1, b2,
                                                 ln2_g, ln2_b, xt, (float*)d_out);
    }
}

// Round 18
// 247.393 us; speedup vs baseline: 1.0594x; 1.0153x over previous
//
#include <hip/hip_runtime.h>
#include <hip/hip_bf16.h>
#include <cstdint>

typedef __attribute__((ext_vector_type(8))) short short8;
typedef __attribute__((ext_vector_type(4))) short short4_;
typedef __attribute__((ext_vector_type(4))) float float4_;
typedef __attribute__((ext_vector_type(16))) float f32x16;

#define MFMA16(a,b,c)  __builtin_amdgcn_mfma_f32_16x16x32_bf16(a,b,c,0,0,0)
#define MFMA32(a,b,c)  __builtin_amdgcn_mfma_f32_32x32x16_bf16(a,b,c,0,0,0)
#define EXP2(x) __builtin_amdgcn_exp2f(x)

// fast bf16 RNE: bit-identical to __float2bfloat16 for all non-NaN inputs.
__device__ __forceinline__ short f2bs(float f) {
    union { float f; uint32_t u; } c;
    c.f = f;
    c.u += 0x7FFF + ((c.u >> 16) & 1);
    return (short)(c.u >> 16);
}
__device__ __forceinline__ float s2f(short s) {
    union { uint32_t u; float f; } c;
    c.u = ((uint32_t)(uint16_t)s) << 16;
    return c.f;
}

static const int EMB = 256;
static const int SEQ = 4096;   // 64*64 spatial
static const int TOK = 16384;  // BS * SEQ

static const size_t SZO = 4194304;   // shorts per O-partial (8 MB)
static const size_t LSTRIDE = 65536; // floats per l-partial (256 KB)

// Attention scale folded into wq/bq: (1/8) * log2(e) -> softmax in exp2 domain.
#define QSCALE 0.18033688011112042f

// ---------------------------------------------------------------- repack ----
__global__ __launch_bounds__(256) void repack_kernel(
    const float* wq, const float* wk, const float* wv,
    const float* wo, const float* w1, const float* w2,
    short* wqT, short* wkT, short* wvT, short* woT, short* w1T, short* w2T)
{
    int idx = blockIdx.x * 256 + threadIdx.x;
    if (idx < 3 * 4096) {
        int m = idx / 4096, r = idx % 4096;
        int n = r / 64, k = r % 64;
        const float* src = (m == 0) ? wq : (m == 1) ? wk : wv;
        short* dst = (m == 0) ? wqT : (m == 1) ? wkT : wvT;
        float v = src[k * 64 + n];
        if (m == 0) v *= QSCALE;
        dst[n * 64 + k] = f2bs(v);
    } else {
        int idx2 = idx - 3 * 4096;
        if (idx2 < 3 * 65536) {
            int m = idx2 / 65536, r = idx2 % 65536;
            int n = r / 256, k = r % 256;
            const float* src = (m == 0) ? wo : (m == 1) ? w1 : w2;
            short* dst = (m == 0) ? woT : (m == 1) ? w1T : w2T;
            dst[n * 256 + k] = f2bs(src[k * 256 + n]);
        }
    }
}

// ---------------------------------------------------------------- ln1qkv ----
// v2 (verbatim — round-11..16 best): 512-thread / 8-wave.
__global__ __launch_bounds__(512, 2) void ln1qkv_kernel(
    const float* x, const float* g, const float* bta,
    const short* wqT, const short* wkT, const short* wvT,
    const float* bq, const float* bk, const float* bv,
    short* xt, short* qo, short* ko, short* vto)
{
    __shared__ short xn_lds[64 * 264];          // 33.8 KB
    __shared__ float redS[8][64], redQ[8][64];  // 4 KB

    int tid = threadIdx.x;
    int l = tid & 63;          // token lane
    int cp = tid >> 6;         // channel part 0..7 (32 channels each)
    int t = blockIdx.x * 64 + l;
    int b = t >> 12, sp = t & 4095;
    const float* xb = x + (size_t)b * EMB * SEQ + (size_t)(cp * 32) * SEQ + sp;

    // ---- phase 1: LN ----
    float v[32];
#pragma unroll
    for (int j = 0; j < 32; j++) v[j] = xb[(size_t)j * SEQ];
    float sum = 0.f, ss = 0.f;
#pragma unroll
    for (int j = 0; j < 32; j++) { sum += v[j]; ss += v[j] * v[j]; }
    redS[cp][l] = sum;
    redQ[cp][l] = ss;
    __syncthreads();
    float S = 0.f, Q = 0.f;
#pragma unroll
    for (int p = 0; p < 8; p++) { S += redS[p][l]; Q += redQ[p][l]; }
    float mu = S * (1.f / 256.f);
    float var = Q * (1.f / 256.f) - mu * mu;
    float rs = rsqrtf(var + 1e-5f);

    short* xtr = xt + (size_t)t * 256 + cp * 32;
    short* xnr = xn_lds + l * 264 + cp * 32;
#pragma unroll
    for (int c = 0; c < 32; c += 8) {
        short8 ra, na;
#pragma unroll
        for (int j = 0; j < 8; j++) {
            float vv = v[c + j];
            ra[j] = f2bs(vv);
            na[j] = f2bs((vv - mu) * rs * g[cp * 32 + c + j] + bta[cp * 32 + c + j]);
        }
        *(short8*)(xtr + c) = ra;
        *(short8*)(xnr + c) = na;
    }
    __syncthreads();

    // ---- phase 2: projections (wave pair per 16-token tile) ----
    int w = tid >> 6;          // wave 0..7
    int lane = tid & 63, quad = lane >> 4, l15 = lane & 15;
    int tt = w >> 1;           // token tile 0..3
    int odd = w & 1;
    int m0 = blockIdx.x * 64 + tt * 16;
    int row = m0 + l15;
    int bb = row >> 12;

    const short* arow = xn_lds + (tt * 16 + l15) * 264;
    short8 a0[4], a1[4];
#pragma unroll
    for (int h = 0; h < 4; h++) {
        a0[h] = *(const short8*)(arow + h * 64 + quad * 8);
        a1[h] = *(const short8*)(arow + h * 64 + 32 + quad * 8);
    }

    // q (even wave) or k (odd wave), full nb 0..3
    {
        const short* WT = odd ? wkT : wqT;
        const float* bias = odd ? bk : bq;
        float bscale = odd ? 1.f : QSCALE;
        short* dst = odd ? ko : qo;
        int s0 = (m0 & 4095) + quad * 4;
#pragma unroll
        for (int nb = 0; nb < 4; nb++) {
            int col = nb * 16 + l15;
            short8 b0 = *(const short8*)(WT + col * 64 + quad * 8);
            short8 b1 = *(const short8*)(WT + col * 64 + 32 + quad * 8);
            float bvv = bias[col] * bscale;
#pragma unroll
            for (int h = 0; h < 4; h++) {
                float4_ acc = {bvv, bvv, bvv, bvv};
                acc = MFMA16(a0[h], b0, acc);
                acc = MFMA16(a1[h], b1, acc);
                size_t headbase = (size_t)(bb * 4 + h) * SEQ;
#pragma unroll
                for (int r = 0; r < 4; r++)
                    dst[(headbase + s0 + r) * 64 + col] = f2bs(acc[r]);
            }
        }
    }

    // V^T half: even wave nb{0,1}, odd wave nb{2,3}
    {
        int sp0 = m0 & 4095;
#pragma unroll
        for (int nbi = 0; nbi < 2; nbi++) {
            int nb = odd * 2 + nbi;
            int colw = nb * 16 + l15;
            short8 b0 = *(const short8*)(wvT + colw * 64 + quad * 8);
            short8 b1 = *(const short8*)(wvT + colw * 64 + 32 + quad * 8);
            float4_ binit;
#pragma unroll
            for (int r = 0; r < 4; r++) binit[r] = bv[nb * 16 + quad * 4 + r];
#pragma unroll
            for (int h = 0; h < 4; h++) {
                float4_ acc = binit;
                acc = MFMA16(b0, a0[h], acc);   // A=weight rows (d), B=xn rows (token)
                acc = MFMA16(b1, a1[h], acc);
                size_t dbase = ((size_t)(bb * 4 + h) * 64 + nb * 16 + quad * 4) * SEQ;
#pragma unroll
                for (int r = 0; r < 4; r++)
                    vto[dbase + (size_t)r * SEQ + sp0 + l15] = f2bs(acc[r]);
            }
        }
    }
}

// ----------------------------------------------------------------- flash ----
// v16 (resubmit — round 17 was an infra failure, no kernel verdict):
// v15 math + 256-ROW Q-BLOCK (512 threads, 8 waves, qt grid 16).
// Mechanism: each (bh,grp) K/V half-span was re-read by 32 qt-blocks
// (L2 thrash -> FETCH 71.7 MB >> ~25 ideal). Doubling q-rows per block
// HALVES per-q-row staging: global K/V reads, ds_writes, barriers.
// Per-wave compute is byte-identical (wave owns 32 q-rows; w now 0..7).
// Staging decomposition: (srow=tid>>3 0..63, c0=tid&7); per thread
// 2 K-writes (rows srow, srow+64) + 2 V-writes (chunks c0, c0+8;
// slot map (j&8)|((j&7)^sw) matches the read map). Prefetch 4 loads.
// Occupancy unchanged: 2 blocks/CU x 8 waves = 16 waves/CU.
__global__ __attribute__((amdgpu_flat_work_group_size(512, 512),
                          amdgpu_waves_per_eu(2, 4)))
void flash_kernel(
    const short* q, const short* k, const short* vt,
    short* O0, short* Orest, float* lbase)
{
    __shared__ short K_lds[128 * 64];   // 16 KB: [krow 0..127][d 0..63]
    __shared__ short V_lds[64 * 128];   // 16 KB: [d 0..63][token 0..127]

    int tid = threadIdx.x;
    int w = tid >> 6, lane = tid & 63;
    int l31 = lane & 31, hh = lane >> 5;
    int qt = blockIdx.x, bh = blockIdx.y, grp = blockIdx.z;
    int span = 64 / gridDim.z;          // 64-row k-tiles per block (even)
    int nst = span >> 1;                // 128-row stages

    const short* qb = q + (size_t)bh * SEQ * 64;
    const short* kb = k + (size_t)bh * SEQ * 64 + (size_t)grp * span * 64 * 64;
    const short* vb = vt + (size_t)bh * 64 * SEQ + grp * span * 64;

    int qrow = qt * 256 + w * 32 + l31;
    // Q B-fragments: B[n=q=l31][k(d) = kb4*16 + hh*8 + j]
    short8 qf[4];
#pragma unroll
    for (int kb4 = 0; kb4 < 4; kb4++)
        qf[kb4] = *(const short8*)(qb + (size_t)qrow * 64 + kb4 * 16 + hh * 8);

    f32x16 oacc[2];   // O^T[d = td*32 + (reg&3)+8*(reg>>2)+4*hh][q = l31]
#pragma unroll
    for (int td = 0; td < 2; td++)
#pragma unroll
        for (int i = 0; i < 16; i++) oacc[td][i] = 0.f;
    float li = 0.f;

    int srow = tid >> 3;          // 0..63
    int c0 = tid & 7;             // chunk (16B units) 0..7
    // write-balanced swizzle: s(row) = (row&7) ^ ((row&1)<<2)
    int sw = (srow & 7) ^ ((srow & 1) << 2);
    int rw = (l31 & 7) ^ ((l31 & 1) << 2);

    int dcK = (c0 ^ sw) << 3;                 // K chunk slot (both row halves)
    int dcV0 = (c0 ^ sw) << 3;                // V chunk c0 (<8)
    int dcV1 = (8 | (c0 ^ sw)) << 3;          // V chunk c0+8

    // prologue: stage stage-0 (k-rows 0..127) into registers
    short8 kr0 = *(const short8*)(kb + (size_t)srow * 64 + c0 * 8);
    short8 kr1 = *(const short8*)(kb + (size_t)(64 + srow) * 64 + c0 * 8);
    short8 vr0 = *(const short8*)(vb + (size_t)srow * SEQ + c0 * 8);
    short8 vr1 = *(const short8*)(vb + (size_t)srow * SEQ + 64 + c0 * 8);

    for (int st = 0; st < nst; st++) {
        __syncthreads();          // prev-stage LDS reads done
        *(short8*)&K_lds[srow * 64 + dcK] = kr0;
        *(short8*)&K_lds[(64 + srow) * 64 + dcK] = kr1;
        *(short8*)&V_lds[srow * 128 + dcV0] = vr0;
        *(short8*)&V_lds[srow * 128 + dcV1] = vr1;
        if (st + 1 < nst) {       // prefetch next stage; in flight across barrier
            size_t ko = (size_t)((st + 1) * 128 + srow) * 64;
            kr0 = *(const short8*)(kb + ko + c0 * 8);
            kr1 = *(const short8*)(kb + ko + 64 * 64 + c0 * 8);
            size_t vo = (size_t)srow * SEQ + (st + 1) * 128;
            vr0 = *(const short8*)(vb + vo + c0 * 8);
            vr1 = *(const short8*)(vb + vo + 64 + c0 * 8);
        }
        asm volatile("s_waitcnt lgkmcnt(0)" ::: "memory");  // my ds_writes done
        __builtin_amdgcn_s_barrier();                       // no vmcnt(0) drain
        asm volatile("" ::: "memory");

#pragma unroll
        for (int t = 0; t < 4; t++) {
            // ---- QK^T: S[kcol = t*32 + ...][q], 4x MFMA 32x32x16 ----
            f32x16 acc;
#pragma unroll
            for (int i = 0; i < 16; i++) acc[i] = 0.f;
#pragma unroll
            for (int kb4 = 0; kb4 < 4; kb4++) {
                short8 ka = *(const short8*)&K_lds[(t * 32 + l31) * 64 +
                                                   (((kb4 * 2 + hh) ^ rw) << 3)];
                acc = MFMA32(ka, qf[kb4], acc);
            }
            // ---- exp2 (in place) + row-sum (q is lane-local) ----
#pragma unroll
            for (int i = 0; i < 16; i++) acc[i] = EXP2(acc[i]);
            li += ((acc[0] + acc[1]) + (acc[2] + acc[3]))
                + ((acc[4] + acc[5]) + (acc[6] + acc[7]))
                + ((acc[8] + acc[9]) + (acc[10] + acc[11]))
                + ((acc[12] + acc[13]) + (acc[14] + acc[15]));
            // ---- pack P -> PV B-frags via cvt_pk + permlane32_swap ----
            short8 wf[2];
#pragma unroll
            for (int kbl = 0; kbl < 2; kbl++) {
                uint32_t A0, A1, B0, B1;
                asm("v_cvt_pk_bf16_f32 %0, %1, %2" : "=v"(A0)
                    : "v"(acc[kbl * 8 + 0]), "v"(acc[kbl * 8 + 1]));
                asm("v_cvt_pk_bf16_f32 %0, %1, %2" : "=v"(A1)
                    : "v"(acc[kbl * 8 + 2]), "v"(acc[kbl * 8 + 3]));
                asm("v_cvt_pk_bf16_f32 %0, %1, %2" : "=v"(B0)
                    : "v"(acc[kbl * 8 + 4]), "v"(acc[kbl * 8 + 5]));
                asm("v_cvt_pk_bf16_f32 %0, %1, %2" : "=v"(B1)
                    : "v"(acc[kbl * 8 + 6]), "v"(acc[kbl * 8 + 7]));
                // after swap: A = [A_lo|B_lo] (= w0/w1), B = [A_hi|B_hi] (= w2/w3)
                asm("v_permlane32_swap_b32 %0, %1" : "+v"(A0), "+v"(B0));
                asm("v_permlane32_swap_b32 %0, %1" : "+v"(A1), "+v"(B1));
                union { short8 s; uint32_t u[4]; } pw;
                pw.u[0] = A0; pw.u[1] = A1; pw.u[2] = B0; pw.u[3] = B1;
                wf[kbl] = pw.s;
            }
            // ---- PV: O^T += V^T-frag x P-frag, 4x MFMA 32x32x16 ----
            __builtin_amdgcn_s_setprio(1);
#pragma unroll
            for (int kbl = 0; kbl < 2; kbl++) {
                int kc = (t * 2 + kbl) * 2 + hh;              // token chunk 0..15
                int kcs = (kc & 8) | ((kc & 7) ^ rw);          // swizzled slot
#pragma unroll
                for (int td = 0; td < 2; td++) {
                    short8 va = *(const short8*)&V_lds[(td * 32 + l31) * 128 +
                                                       (kcs << 3)];
                    oacc[td] = MFMA32(va, wf[kbl], oacc[td]);
                }
            }
            __builtin_amdgcn_s_setprio(0);
        }
    }

    li += __shfl_xor(li, 32);

    short* Op = grp ? (Orest + (size_t)(grp - 1) * SZO) : O0;
    float* lp = lbase + (size_t)grp * LSTRIDE;
    if (hh == 0) lp[bh * 4096 + qrow] = li;

    size_t ob = ((size_t)bh * 4096 + qrow) * 64;
#pragma unroll
    for (int td = 0; td < 2; td++)
#pragma unroll
        for (int g = 0; g < 4; g++) {
            short4_ pk;
#pragma unroll
            for (int r = 0; r < 4; r++) pk[r] = f2bs(oacc[td][g * 4 + r]);
            *(short4_*)(Op + ob + td * 32 + g * 8 + hh * 4) = pk;
        }
}

// --------------------------------------------------------------- combine ----
// Fallback path only: out = (sum of np partials) / (sum of np l's).
__global__ __launch_bounds__(256) void combine_kernel(
    const short* O0, const short* Orest, const float* lb,
    short* Oout, int np)
{
    int g = blockIdx.x * 256 + threadIdx.x;     // short4 units, 1048576 total
    int qi = g >> 4;
    short4_ a = *(const short4_*)(O0 + (size_t)g * 4);
    float l = lb[qi];
    float4_ acc = {s2f(a[0]), s2f(a[1]), s2f(a[2]), s2f(a[3])};
    for (int j = 1; j < np; j++) {
        short4_ b = *(const short4_*)(Orest + (size_t)(j - 1) * SZO + (size_t)g * 4);
        l += lb[(size_t)j * LSTRIDE + qi];
#pragma unroll
        for (int jj = 0; jj < 4; jj++) acc[jj] += s2f(b[jj]);
    }
    float inv = 1.f / l;
    short4_ pk;
#pragma unroll
    for (int j = 0; j < 4; j++) pk[j] = f2bs(acc[j] * inv);
    *(short4_*)(Oout + (size_t)g * 4) = pk;
}

// ------------------------------------------------------------------- mlp ----
// v2 (verbatim — round-16, measured equal to v1 with less L2 traffic):
// 32-token tiles, 512 threads / 8 waves.
__global__ __launch_bounds__(512, 2) void mlp_kernel(
    const short* O0, const short* Orest, const float* lb, int np,
    const short* woT, const short* w1T, const short* w2T,
    const float* bo, const float* b1, const float* b2,
    const float* g2, const float* be2,
    const short* xt, float* outf)
{
    __shared__ __align__(16) char smem[3 * 16896 + 256];
    short* av = (short*)smem;                   // [32][264] bf16
    short* x2 = (short*)(smem + 16896);         // [32][264] bf16
    short* ff = (short*)(smem + 33792);         // [32][264] bf16
    float* stats = (float*)(smem + 50688);      // mu[32], rs[32]
    float* T = (float*)smem;                    // alias av|x2 (33.3 <= 33.8 KB)

    int tid = threadIdx.x;
    int w = tid >> 6, lane = tid & 63, quad = lane >> 4, l15 = lane & 15;
    int m0 = blockIdx.x * 32;
    int th = w >> 2;                // token half 0..1
    int n0 = (w & 3) * 64;          // col slice
    int arow = m0 + th * 16 + l15;
    int bbA = arow >> 12, spA = arow & 4095;

    // per-(head,token) normalizers (loop-invariant, small cached loads)
    float invh[4];
    if (np) {
#pragma unroll
        for (int h = 0; h < 4; h++) {
            size_t li = (size_t)(bbA * 4 + h) * 4096 + spA;
            float s = lb[li];
            for (int j = 1; j < np; j++) s += lb[(size_t)j * LSTRIDE + li];
            invh[h] = 1.f / s;
        }
    }

    // ---- stage A: attention out-proj + xt residual -> av (LDS bf16) ----
    float4_ acc[4];
#pragma unroll
    for (int nb = 0; nb < 4; nb++) {
        float bvv = bo[n0 + nb * 16 + l15];
        acc[nb] = {bvv, bvv, bvv, bvv};
    }
    for (int kc = 0; kc < 8; kc++) {
        int h = kc >> 1;
        int off = (kc & 1) * 32 + quad * 8;
        size_t obase = ((size_t)(bbA * 4 + h) * 4096 + spA) * 64 + off;
        short8 a;
        if (np) {
            short8 a0v = *(const short8*)(O0 + obase);
            float f[8];
#pragma unroll
            for (int jj = 0; jj < 8; jj++) f[jj] = s2f(a0v[jj]);
            for (int j = 1; j < np; j++) {
                short8 apv = *(const short8*)(Orest + (size_t)(j - 1) * SZO + obase);
#pragma unroll
                for (int jj = 0; jj < 8; jj++) f[jj] += s2f(apv[jj]);
            }
            float iv = invh[h];
            union { short8 s; uint32_t u[4]; } pa;
#pragma unroll
            for (int jj = 0; jj < 4; jj++) {
                float f0 = f[2 * jj] * iv;
                float f1 = f[2 * jj + 1] * iv;
                asm("v_cvt_pk_bf16_f32 %0, %1, %2" : "=v"(pa.u[jj]) : "v"(f0), "v"(f1));
            }
            a = pa.s;
        } else {
            a = *(const short8*)(O0 + obase);
        }
#pragma unroll
        for (int nb = 0; nb < 4; nb++) {
            short8 b = *(const short8*)(woT + (size_t)(n0 + nb * 16 + l15) * 256 + kc * 32 + quad * 8);
            acc[nb] = MFMA16(a, b, acc[nb]);
        }
    }
#pragma unroll
    for (int nb = 0; nb < 4; nb++) {
        int col = n0 + nb * 16 + l15;
#pragma unroll
        for (int r = 0; r < 4; r++) {
            size_t t = (size_t)m0 + th * 16 + quad * 4 + r;
            av[(th * 16 + quad * 4 + r) * 264 + col] = f2bs(acc[nb][r] + s2f(xt[t * 256 + col]));
        }
    }
    __syncthreads();

    // ---- stage B: LN2 stats (16 threads per row, 32 rows) ----
    {
        int row = tid >> 4, sub = tid & 15;
        float sum = 0.f, ss = 0.f;
        short8 v0 = *(const short8*)&av[row * 264 + sub * 16];
        short8 v1 = *(const short8*)&av[row * 264 + sub * 16 + 8];
#pragma unroll
        for (int j = 0; j < 8; j++) {
            float a = s2f(v0[j]), b = s2f(v1[j]);
            sum += a + b; ss += a * a + b * b;
        }
#pragma unroll
        for (int off = 1; off < 16; off <<= 1) {
            sum += __shfl_xor(sum, off);
            ss += __shfl_xor(ss, off);
        }
        if (sub == 0) {
            float mu = sum * (1.f / 256.f);
            float var = ss * (1.f / 256.f) - mu * mu;
            stats[row] = mu;
            stats[32 + row] = rsqrtf(var + 1e-5f);
        }
    }
    __syncthreads();

    // ---- stage C: xn2 = (av - mu) * rs * g2 + be2 (LDS bf16) ----
    {
        int row = tid >> 4, sub = tid & 15;
        float mu = stats[row], rs = stats[32 + row];
#pragma unroll
        for (int j = 0; j < 16; j += 4) {
            int c = sub * 16 + j;
            short4_ rv = *(const short4_*)&av[row * 264 + c];
            short4_ pk;
#pragma unroll
            for (int i = 0; i < 4; i++)
                pk[i] = f2bs((s2f(rv[i]) - mu) * rs * g2[c + i] + be2[c + i]);
            *(short4_*)&x2[row * 264 + c] = pk;
        }
    }
    __syncthreads();

    // ---- stage D: gemm1 + exact GELU -> ff (LDS bf16) ----
#pragma unroll
    for (int nb = 0; nb < 4; nb++) {
        float bvv = b1[n0 + nb * 16 + l15];
        acc[nb] = {bvv, bvv, bvv, bvv};
    }
    for (int kc = 0; kc < 8; kc++) {
        short8 a = *(const short8*)&x2[(th * 16 + l15) * 264 + kc * 32 + quad * 8];
#pragma unroll
        for (int nb = 0; nb < 4; nb++) {
            short8 b = *(const short8*)(w1T + (size_t)(n0 + nb * 16 + l15) * 256 + kc * 32 + quad * 8);
            acc[nb] = MFMA16(a, b, acc[nb]);
        }
    }
#pragma unroll
    for (int nb = 0; nb < 4; nb++) {
        int col = n0 + nb * 16 + l15;
#pragma unroll
        for (int r = 0; r < 4; r++) {
            float v = acc[nb][r];
            v = 0.5f * v * (1.f + erff(v * 0.70710678118f));
            ff[(th * 16 + quad * 4 + r) * 264 + col] = f2bs(v);
        }
    }
    __syncthreads();

    // ---- stage E: gemm2 + av residual ----
#pragma unroll
    for (int nb = 0; nb < 4; nb++) {
        float bvv = b2[n0 + nb * 16 + l15];
        acc[nb] = {bvv, bvv, bvv, bvv};
    }
    for (int kc = 0; kc < 8; kc++) {
        short8 a = *(const short8*)&ff[(th * 16 + l15) * 264 + kc * 32 + quad * 8];
#pragma unroll
        for (int nb = 0; nb < 4; nb++) {
            short8 b = *(const short8*)(w2T + (size_t)(n0 + nb * 16 + l15) * 256 + kc * 32 + quad * 8);
            acc[nb] = MFMA16(a, b, acc[nb]);
        }
    }
    float vout[4][4];
#pragma unroll
    for (int nb = 0; nb < 4; nb++) {
        int col = n0 + nb * 16 + l15;
#pragma unroll
        for (int r = 0; r < 4; r++)
            vout[nb][r] = acc[nb][r] + s2f(av[(th * 16 + quad * 4 + r) * 264 + col]);
    }
    __syncthreads();   // all reads of av/x2/ff complete before T alias writes

    // wave-private fp32 transpose -> coalesced [b][c][sp] stores
    float* tw = T + w * 1040;
#pragma unroll
    for (int nb = 0; nb < 4; nb++)
#pragma unroll
        for (int r = 0; r < 4; r++)
            tw[(quad * 4 + r) * 65 + nb * 16 + l15] = vout[nb][r];

    int bb = m0 >> 12;
    int spb = (m0 & 4095) + th * 16;
    float* dst = outf + ((size_t)bb * 256 + n0 + lane) * SEQ + spb;
#pragma unroll
    for (int j = 0; j < 16; j += 4) {
        float4_ pk = {tw[(j + 0) * 65 + lane], tw[(j + 1) * 65 + lane],
                      tw[(j + 2) * 65 + lane], tw[(j + 3) * 65 + lane]};
        *(float4_*)(dst + j) = pk;
    }
}

// ---------------------------------------------------------------- launch ----
// Chain: repack -> ln1qkv (fused) -> flash (BK=128, 256-row q-blocks) ->
// [combine] -> mlp (32-token tiles). Tiers: nz=2 fused (ws >= 41 MB) /
// nz=2 split (>= 33) / nz=1.
extern "C" void kernel_launch(void* const* d_in, const int* in_sizes, int n_in,
                              void* d_out, int out_size, void* d_ws, size_t ws_size,
                              hipStream_t stream)
{
    const float* x     = (const float*)d_in[0];
    const float* ln1_g = (const float*)d_in[1];
    const float* ln1_b = (const float*)d_in[2];
    const float* wq    = (const float*)d_in[3];
    const float* bq    = (const float*)d_in[4];
    const float* wk    = (const float*)d_in[5];
    const float* bk    = (const float*)d_in[6];
    const float* wv    = (const float*)d_in[7];
    const float* bv    = (const float*)d_in[8];
    const float* wo    = (const float*)d_in[9];
    const float* bo    = (const float*)d_in[10];
    const float* ln2_g = (const float*)d_in[11];
    const float* ln2_b = (const float*)d_in[12];
    const float* w1    = (const float*)d_in[13];
    const float* b1    = (const float*)d_in[14];
    const float* w2    = (const float*)d_in[15];
    const float* b2    = (const float*)d_in[16];

    char* ws = (char*)d_ws;
    const size_t SZ_BF = (size_t)TOK * 256 * 2;  // 8 MB

    short* wqT = (short*)(ws + 0);
    short* wkT = (short*)(ws + 8192);
    short* wvT = (short*)(ws + 16384);
    short* woT = (short*)(ws + 24576);
    short* w1T = (short*)(ws + 155648);
    short* w2T = (short*)(ws + 286720);
    char* base = ws + 524288;

    short* xt  = (short*)(base);
    short* kbuf= (short*)(base + SZ_BF);
    short* vtb = (short*)(base + 2 * SZ_BF);

    const size_t need2_fb = 524288 + 3 * SZ_BF + 524288 + SZ_BF;      // 33.0 MB
    const size_t need2_fu = need2_fb + SZ_BF;                          // 41.0 MB

    int nz, fuse;
    if (ws_size >= need2_fu)      { nz = 2; fuse = 1; }
    else if (ws_size >= need2_fb) { nz = 2; fuse = 0; }
    else                          { nz = 1; fuse = 0; }

    float* lbase = (float*)(base + 3 * SZ_BF);              // 2 x 256 KB
    short* Orest = (short*)(base + 3 * SZ_BF + 524288);     // O1
    short* O0w   = Orest + SZO;                             // fused only

    short* qb  = (short*)d_out;                      // lower 8 MB
    short* upper = (short*)((char*)d_out + SZ_BF);   // upper 8 MB (O0 in split)
    short* O0  = fuse ? O0w : upper;                 // partial O (grp 0)
    short* Onrm= vtb;                                // normalized O (fallback)

    repack_kernel<<<816, 256, 0, stream>>>(wq, wk, wv, wo, w1, w2,
                                           wqT, wkT, wvT, woT, w1T, w2T);
    ln1qkv_kernel<<<TOK / 64, 512, 0, stream>>>(x, ln1_g, ln1_b,
                                                wqT, wkT, wvT, bq, bk, bv,
                                                xt, qb, kbuf, vtb);
    flash_kernel<<<dim3(16, 16, nz), 512, 0, stream>>>(qb, kbuf, vtb, O0, Orest, lbase);
    if (fuse) {
        mlp_kernel<<<TOK / 32, 512, 0, stream>>>(O0, Orest, lbase, nz,
                                                 woT, w1T, w2T, bo, b1, b2,
                                                 ln2_g, ln2_b, xt, (float*)d_out);
    } else {
        combine_kernel<<<4096, 256, 0, stream>>>(O0, Orest, lbase, Onrm, nz);
        mlp_kernel<<<TOK / 32, 512, 0, stream>>>(Onrm, Orest, lbase, 0,
                                                 woT, w1T, w2T, bo, b1, b2,
                                                 ln2_g, ln2_b, xt, (float*)d_out);
    }
}